// Round 6
// baseline (741.455 us; speedup 1.0000x reference)
//
#include <hip/hip_runtime.h>

#define INV_SQRT_2 0.70710678118654752440f
#define INV_SQRT_3 0.57735026918962576451f

typedef __bf16 bf16_t;
typedef __bf16 bf16x8 __attribute__((ext_vector_type(8)));
typedef __bf16 bf16x4 __attribute__((ext_vector_type(4)));
typedef float f32x4 __attribute__((ext_vector_type(4)));

__device__ __forceinline__ float toF(float x) { return x; }
__device__ __forceinline__ float toF(bf16_t x) { return (float)x; }
__device__ __forceinline__ float siluf(float x) { return x / (1.f + __expf(-x)); }

__device__ __forceinline__ bf16x8 ld8(const bf16_t* p) { return *(const bf16x8*)p; }
__device__ __forceinline__ bf16x8 ld8(const float* p) {
  bf16x8 r;
#pragma unroll
  for (int j = 0; j < 8; ++j) r[j] = (bf16_t)p[j];
  return r;
}

// runtime-dtype scalar load
__device__ __forceinline__ float ldsc(const void* p, int f32, size_t i) {
  return f32 ? ((const float*)p)[i] : toF(((const bf16_t*)p)[i]);
}

__device__ __forceinline__ f32x4 MFMA(bf16x8 a, bf16x8 b, f32x4 c) {
  return __builtin_amdgcn_mfma_f32_16x16x32_bf16(a, b, c, 0, 0, 0);
}

__device__ __forceinline__ void zero8(f32x4 (&a)[8]) {
#pragma unroll
  for (int i = 0; i < 8; ++i)
#pragma unroll
    for (int q = 0; q < 4; ++q) a[i][q] = 0.f;
}
__device__ __forceinline__ void zero4(f32x4 (&a)[4]) {
#pragma unroll
  for (int i = 0; i < 4; ++i)
#pragma unroll
    for (int q = 0; q < 4; ++q) a[i][q] = 0.f;
}

// Packed-B fragment: element j of lane l = B[ks*32 + (l>>4)*8 + j][nt*16 + (l&15)]
__device__ __forceinline__ bf16x8 ldB(const bf16_t* Bp, int ks, int nt, int NT, int lane) {
  return *(const bf16x8*)(Bp + ((((size_t)ks * NT + nt) * 64 + lane) << 3));
}

// A-fragment loader: 4 chunks of 8, row stride 128, runtime dtype
__device__ __forceinline__ void ldA(bf16x8 (&af)[4], const void* p, int f32, size_t row, int g) {
  if (f32) {
    const float* q = (const float*)p + row * 128 + (g << 3);
#pragma unroll
    for (int ks = 0; ks < 4; ++ks) af[ks] = ld8(q + ks * 32);
  } else {
    const bf16_t* q = (const bf16_t*)p + row * 128 + (g << 3);
#pragma unroll
    for (int ks = 0; ks < 4; ++ks) af[ks] = ld8(q + ks * 32);
  }
}

// ---- weight staging: 256 threads move 32KB (St8) / 16KB (St4) global->regs->LDS ----
struct St8 { bf16x8 v[8]; };
__device__ __forceinline__ void issue8(St8& r, const bf16_t* src, int tid) {
#pragma unroll
  for (int i = 0; i < 8; ++i) r.v[i] = *(const bf16x8*)(src + ((i * 256 + tid) << 3));
}
__device__ __forceinline__ void commit8(const St8& r, bf16_t* dst, int tid) {
#pragma unroll
  for (int i = 0; i < 8; ++i) *(bf16x8*)&dst[(i * 256 + tid) << 3] = r.v[i];
}
struct St4 { bf16x8 v[4]; };
__device__ __forceinline__ void issue4(St4& r, const bf16_t* src, int tid) {
#pragma unroll
  for (int i = 0; i < 4; ++i) r.v[i] = *(const bf16x8*)(src + ((i * 256 + tid) << 3));
}
__device__ __forceinline__ void commit4(const St4& r, bf16_t* dst, int tid) {
#pragma unroll
  for (int i = 0; i < 4; ++i) *(bf16x8*)&dst[(i * 256 + tid) << 3] = r.v[i];
}

// ---- MFMA pass over 16 rows from A-frag regs; B from LDS ----
template <int KS, int NT>
__device__ __forceinline__ void pass_glob(f32x4 (&acc)[NT], const bf16x8* af,
                                          const bf16_t* Wbuf, int lane) {
#pragma unroll
  for (int ks = 0; ks < KS; ++ks)
#pragma unroll
    for (int nt = 0; nt < NT; ++nt)
      acc[nt] = MFMA(af[ks], *(const bf16x8*)&Wbuf[((ks * NT + nt) * 64 + lane) << 3], acc[nt]);
}
// ---- MFMA pass; A from a 16-row LDS slab (stride 136), B from LDS ----
template <int KS>
__device__ __forceinline__ void pass_slab(f32x4 (&acc)[8], const bf16_t* slab,
                                          const bf16_t* Wbuf, int lane) {
  const int rc = lane & 15, g = lane >> 4;
#pragma unroll
  for (int ks = 0; ks < KS; ++ks) {
    bf16x8 a = *(const bf16x8*)&slab[rc * 136 + ks * 32 + (g << 3)];
#pragma unroll
    for (int nt = 0; nt < 8; ++nt)
      acc[nt] = MFMA(a, *(const bf16x8*)&Wbuf[((ks * 8 + nt) * 64 + lane) << 3], acc[nt]);
  }
}

// ---- dtype detector: probe rbf_h (uniform [0,1]) interpreted as bf16 words ----
__global__ void k_detect(const unsigned short* __restrict__ probe, int* __restrict__ flag) {
  __shared__ int cnt;
  if (threadIdx.x == 0) cnt = 0;
  __syncthreads();
  int bad = 0;
  for (int i = threadIdx.x; i < 256; i += 64) {
    unsigned int u = (unsigned int)probe[i] << 16;
    float v = __uint_as_float(u);
    if (!(v == v) || fabsf(v) > 4.f || v < -0.25f) bad++;
  }
  atomicAdd(&cnt, bad);
  __syncthreads();
  if (threadIdx.x == 0) *flag = (cnt > 16) ? 1 : 0;
}

__global__ void k_zero(float* __restrict__ p, int n) {
  int i = blockIdx.x * blockDim.x + threadIdx.x;
  if (i < n) p[i] = 0.f;
}

// ---------------- weight repack: W(KxN) -> fragment-linear [hi|lo] ----------------
// mode = (Koff << 1) | bilinear. Koff: source row offset (stacked weights).
// bilinear: (I=64,B=16,O=64) source, flattened K index kk = b*64 + i.
struct RDesc { const void* src; int K, N, Kpad, dstoff, mode; };
struct RTable { RDesc d[25]; };

__global__ void k_repack(const int* __restrict__ flag, RTable tab, bf16_t* __restrict__ out) {
  const int ws = *flag;
  RDesc d = tab.d[blockIdx.y];
  int p = blockIdx.x * 256 + threadIdx.x;
  int sz = d.Kpad * d.N;
  if (p >= sz) return;
  const int bilin = d.mode & 1;
  const int Koff = d.mode >> 1;
  int NT = d.N >> 4;
  int j = p & 7;
  int lane = (p >> 3) & 63;
  int q = p >> 9;
  int nt = q % NT, ks = q / NT;
  int k = ks * 32 + ((lane >> 4) << 3) + j;
  int col = nt * 16 + (lane & 15);
  size_t si = bilin ? ((size_t)(k & 63) * 16 + (k >> 6)) * 64 + col
                    : (size_t)(k + Koff) * d.N + col;
  float v = (k < d.K) ? ldsc(d.src, ws, si) : 0.f;
  bf16_t hi = (bf16_t)v;
  out[d.dstoff + p] = hi;
  out[d.dstoff + sz + p] = (bf16_t)(v - (float)hi);
}

// ---- MFMA bilinear: 16 edges/block, 256 threads ----
__global__ __launch_bounds__(256) void k_bil(const int* __restrict__ flag,
    const void* __restrict__ basis, const bf16_t* __restrict__ msrc,
    const int* __restrict__ gidx, const bf16_t* __restrict__ Wc,
    bf16_t* __restrict__ out) {
  const int ws = *flag;
  __shared__ __align__(16) bf16_t Ms[96 * 72];
  __shared__ __align__(16) float Bas[16 * 100];
  __shared__ __align__(16) bf16_t P[16384];
  const int tid = threadIdx.x;
  const int e0 = blockIdx.x * 16;
#pragma unroll
  for (int it = 0; it < 3; ++it) {
    int c = tid + it * 256;
    int j = c >> 3, part = c & 7;
    int row = gidx[e0 * 6 + j];
    *(bf16x8*)&Ms[j * 72 + part * 8] = ld8(msrc + (size_t)row * 64 + part * 8);
  }
#pragma unroll
  for (int it = 0; it < 6; ++it) {
    int c = tid + it * 256;
    Bas[(c / 96) * 100 + (c % 96)] = ldsc(basis, ws, (size_t)e0 * 96 + c);
  }
  __syncthreads();
  {
    const int e = tid >> 4, sub = tid & 15, i0 = sub * 4;
    float acc[16][4];
#pragma unroll
    for (int b = 0; b < 16; ++b)
#pragma unroll
      for (int j = 0; j < 4; ++j) acc[b][j] = 0.f;
#pragma unroll
    for (int k = 0; k < 6; ++k) {
      bf16x4 mv = *(const bf16x4*)&Ms[(e * 6 + k) * 72 + i0];
      float mf[4];
#pragma unroll
      for (int j = 0; j < 4; ++j) mf[j] = (float)mv[j];
      const float* bp = &Bas[e * 100 + k * 16];
#pragma unroll
      for (int b4 = 0; b4 < 4; ++b4) {
        f32x4 bv = *(const f32x4*)&bp[b4 * 4];
#pragma unroll
        for (int bb = 0; bb < 4; ++bb)
#pragma unroll
          for (int j = 0; j < 4; ++j) acc[b4 * 4 + bb][j] += bv[bb] * mf[j];
      }
    }
#pragma unroll
    for (int b = 0; b < 16; ++b) {
      int kk = b * 64 + i0;
      int ks = kk >> 5, r5 = kk & 31;
      int lane_hi = r5 >> 3, jj = r5 & 7;
      bf16x4 w;
#pragma unroll
      for (int j = 0; j < 4; ++j) w[j] = (bf16_t)acc[b][j];
      *(bf16x4*)&P[ks * 512 + lane_hi * 128 + e * 8 + jj] = w;
    }
  }
  __syncthreads();
  const int lane = tid & 63, wid = tid >> 6;
  const int rc = lane & 15, g = lane >> 4;
  f32x4 oa[4];
  zero4(oa);
  if (ws) {
#pragma unroll
    for (int k4 = 0; k4 < 8; ++k4)
#pragma unroll
      for (int j = 0; j < 4; ++j) {
        int ks = k4 * 4 + j;
        bf16x8 a = *(const bf16x8*)&P[ks * 512 + lane * 8];
        oa[j] = MFMA(a, ldB(Wc, ks, wid, 4, lane), oa[j]);
        oa[j] = MFMA(a, ldB(Wc + 65536, ks, wid, 4, lane), oa[j]);
      }
  } else {
#pragma unroll
    for (int k4 = 0; k4 < 8; ++k4)
#pragma unroll
      for (int j = 0; j < 4; ++j) {
        int ks = k4 * 4 + j;
        bf16x8 a = *(const bf16x8*)&P[ks * 512 + lane * 8];
        oa[j] = MFMA(a, ldB(Wc, ks, wid, 4, lane), oa[j]);
      }
  }
  f32x4 oacc = (oa[0] + oa[1]) + (oa[2] + oa[3]);
  bf16_t* op = out + ((size_t)e0 + g * 4) * 64 + wid * 16 + rc;
#pragma unroll
  for (int r = 0; r < 4; ++r) op[(size_t)r * 64] = (bf16_t)oacc[r];
}

// ---- m_kt pre: silu(m_st@Wm) * (rbf3@Wr); 64 rows/block ----
__global__ __launch_bounds__(256, 2) void k_mkt2(const int* __restrict__ flag,
    const void* __restrict__ mst, const void* __restrict__ rbf3,
    const bf16_t* __restrict__ Wm, const bf16_t* __restrict__ Wr,
    bf16_t* __restrict__ out) {
  const int ws = *flag;
  __shared__ __align__(16) bf16_t Wb[2][16384];
  __shared__ __align__(16) bf16_t Wrl[8192];
  const int tid = threadIdx.x;
  const int lane = tid & 63, wid = tid >> 6;
  const int grow0 = blockIdx.x * 64 + wid * 16;
  const int rc = lane & 15, g = lane >> 4;
  St8 s8;
  issue8(s8, Wm, tid);
  bf16x8 wr[4];
#pragma unroll
  for (int i = 0; i < 4; ++i) wr[i] = *(const bf16x8*)(Wr + ((i * 256 + tid) << 3));
  commit8(s8, Wb[0], tid);
#pragma unroll
  for (int i = 0; i < 4; ++i) *(bf16x8*)&Wrl[(i * 256 + tid) << 3] = wr[i];
  __syncthreads();
  bf16x8 af[4];
  ldA(af, mst, ws, (size_t)(grow0 + rc), g);
  bf16x8 az;
#pragma unroll
  for (int j = 0; j < 8; ++j) az[j] = (bf16_t)0.f;
  if (g < 2) {
    if (ws) az = ld8((const float*)rbf3 + (size_t)(grow0 + rc) * 16 + (g << 3));
    else    az = ld8((const bf16_t*)rbf3 + (size_t)(grow0 + rc) * 16 + (g << 3));
  }
  f32x4 ag[8];
  zero8(ag);
#pragma unroll
  for (int nt = 0; nt < 8; ++nt) {
    ag[nt] = MFMA(az, *(const bf16x8*)&Wrl[(nt * 64 + lane) << 3], ag[nt]);
    if (ws) ag[nt] = MFMA(az, *(const bf16x8*)&Wrl[4096 + ((nt * 64 + lane) << 3)], ag[nt]);
  }
  f32x4 am[8];
  zero8(am);
  if (ws) issue8(s8, Wm + 16384, tid);
  pass_glob<4, 8>(am, af, Wb[0], lane);
  if (ws) {
    commit8(s8, Wb[1], tid);
    __syncthreads();
    pass_glob<4, 8>(am, af, Wb[1], lane);
  }
  bf16_t* op = out + (size_t)(grow0 + g * 4) * 128 + rc;
#pragma unroll
  for (int nt = 0; nt < 8; ++nt)
#pragma unroll
    for (int r = 0; r < 4; ++r)
      op[(size_t)r * 128 + nt * 16] = (bf16_t)(siluf(am[nt][r]) * ag[nt][r]);
}

// ---- GEMM+silu: A(M x 128) @ W(128 x 64); 64 rows/block ----
__global__ __launch_bounds__(256, 4) void k_gemmE2(const int* __restrict__ flag, int a_rt,
    const void* __restrict__ A, const bf16_t* __restrict__ W, bf16_t* __restrict__ out) {
  const int ws = *flag;
  const int af32 = a_rt & ws;
  __shared__ __align__(16) bf16_t Wb[2][8192];
  const int tid = threadIdx.x;
  const int lane = tid & 63, wid = tid >> 6;
  const int grow0 = blockIdx.x * 64 + wid * 16;
  const int rc = lane & 15, g = lane >> 4;
  St4 s4;
  issue4(s4, W, tid);
  commit4(s4, Wb[0], tid);
  __syncthreads();
  bf16x8 af[4];
  ldA(af, A, af32, (size_t)(grow0 + rc), g);
  f32x4 acc[4];
  zero4(acc);
  if (ws) issue4(s4, W + 8192, tid);
  pass_glob<4, 4>(acc, af, Wb[0], lane);
  if (ws) {
    commit4(s4, Wb[1], tid);
    __syncthreads();
    pass_glob<4, 4>(acc, af, Wb[1], lane);
  }
  bf16_t* op = out + (size_t)(grow0 + g * 4) * 64 + rc;
#pragma unroll
  for (int nt = 0; nt < 4; ++nt)
#pragma unroll
    for (int r = 0; r < 4; ++r) op[(size_t)r * 64 + nt * 16] = (bf16_t)siluf(acc[nt][r]);
}

// ---- GEMM+silu: A(N x 128, f32) @ W(128 x 128); 64 rows/block ----
__global__ __launch_bounds__(256, 2) void k_gemmN2(const int* __restrict__ flag,
    const float* __restrict__ A, const bf16_t* __restrict__ W, bf16_t* __restrict__ out) {
  const int ws = *flag;
  __shared__ __align__(16) bf16_t Wb[2][16384];
  const int tid = threadIdx.x;
  const int lane = tid & 63, wid = tid >> 6;
  const int grow0 = blockIdx.x * 64 + wid * 16;
  const int rc = lane & 15, g = lane >> 4;
  St8 s8;
  issue8(s8, W, tid);
  commit8(s8, Wb[0], tid);
  __syncthreads();
  bf16x8 af[4];
  {
    const float* q = A + (size_t)(grow0 + rc) * 128 + (g << 3);
#pragma unroll
    for (int ks = 0; ks < 4; ++ks) af[ks] = ld8(q + ks * 32);
  }
  f32x4 acc[8];
  zero8(acc);
  if (ws) issue8(s8, W + 16384, tid);
  pass_glob<4, 8>(acc, af, Wb[0], lane);
  if (ws) {
    commit8(s8, Wb[1], tid);
    __syncthreads();
    pass_glob<4, 8>(acc, af, Wb[1], lane);
  }
  bf16_t* op = out + (size_t)(grow0 + g * 4) * 128 + rc;
#pragma unroll
  for (int nt = 0; nt < 8; ++nt)
#pragma unroll
    for (int r = 0; r < 4; ++r) op[(size_t)r * 128 + nt * 16] = (bf16_t)siluf(acc[nt][r]);
}

// ---- combine: 64 rows/block, 5 logical GEMMs, double-buffered weights ----
__global__ __launch_bounds__(256, 2) void k_comb2(const int* __restrict__ flag,
    const void* __restrict__ mst, const bf16_t* __restrict__ xt,
    const bf16_t* __restrict__ xq, const int* __restrict__ idx_swap,
    const bf16_t* Wsk, const bf16_t* Wtst, const bf16_t* Wtts,
    const bf16_t* Wqst, const bf16_t* Wqts, bf16_t* __restrict__ X) {
  const int ws = *flag;
  __shared__ __align__(16) bf16_t Wb[2][16384];
  const int tid = threadIdx.x;
  const int lane = tid & 63, wid = tid >> 6;
  const int grow0 = blockIdx.x * 64 + wid * 16;
  const int rc = lane & 15, g = lane >> 4;
  const int arow = grow0 + rc;
  const int srow = idx_swap[arow];
  const bf16_t* wseq[5] = {Wsk, Wtst, Wtts, Wqst, Wqts};
  const int SZs[5] = {16384, 8192, 8192, 8192, 8192};
  St8 s8;
  issue8(s8, wseq[0], tid);
  commit8(s8, Wb[0], tid);
  __syncthreads();
  int cur = 0;
  const int NP = ws ? 2 : 1;
  f32x4 total[8], acc[8];
  zero8(acc);
  bf16x8 af[4];
  for (int l = 0; l < 5; ++l) {
    if (l == 0) {
      ldA(af, mst, ws, (size_t)arow, g);
    } else {
      const bf16_t* asrc = (l <= 2) ? xt : xq;
      int r = (l == 1 || l == 3) ? arow : srow;
      af[0] = ld8(asrc + (size_t)r * 64 + (g << 3));
      af[1] = ld8(asrc + (size_t)r * 64 + 32 + (g << 3));
    }
    for (int p = 0; p < NP; ++p) {
      const bool last = (l == 4) && (p == NP - 1);
      if (!last) issue8(s8, (ws && p == 0) ? wseq[l] + SZs[l] : wseq[l + 1], tid);
      if (l == 0) pass_glob<4, 8>(acc, af, Wb[cur], lane);
      else        pass_glob<2, 8>(acc, af, Wb[cur], lane);
      if (!last) {
        commit8(s8, Wb[cur ^ 1], tid);
        __syncthreads();
        cur ^= 1;
      }
    }
    if (l == 0) {
#pragma unroll
      for (int nt = 0; nt < 8; ++nt) total[nt] = acc[nt] * INV_SQRT_3;
    } else {
#pragma unroll
      for (int nt = 0; nt < 8; ++nt)
#pragma unroll
        for (int r = 0; r < 4; ++r)
          total[nt][r] += siluf(acc[nt][r]) * (INV_SQRT_2 * INV_SQRT_3);
    }
    zero8(acc);
  }
  bf16_t* op = X + (size_t)(grow0 + g * 4) * 128 + rc;
#pragma unroll
  for (int nt = 0; nt < 8; ++nt)
#pragma unroll
    for (int r = 0; r < 4; ++r) op[(size_t)r * 128 + nt * 16] = (bf16_t)total[nt][r];
}

// ---- resE: res_before + mst-mix + res_after(2 layers); 64 rows/block, 2 blk/CU ----
__global__ __launch_bounds__(256, 2) void k_resE2(const int* __restrict__ flag,
    const bf16_t* __restrict__ Xg, const void* __restrict__ mst,
    const bf16_t* W0, const bf16_t* W1, const bf16_t* W2,
    const bf16_t* W3, const bf16_t* W4, const bf16_t* W5,
    bf16_t* __restrict__ outg) {
  const int ws = *flag;
  __shared__ __align__(16) bf16_t Xs[64 * 136];
  __shared__ __align__(16) bf16_t Ys[64 * 136];
  __shared__ __align__(16) bf16_t Wb[16384];
  const int tid = threadIdx.x;
  const int lane = tid & 63, wid = tid >> 6;
  const int grow0 = blockIdx.x * 64 + wid * 16;
  const int rc = lane & 15, g = lane >> 4;
  bf16_t* slabX = Xs + wid * (16 * 136);
  bf16_t* slabY = Ys + wid * (16 * 136);
  const bf16_t* Wl[6] = {W0, W1, W2, W3, W4, W5};
  const bf16_t* seq[12];
  int NW;
  if (ws) {
    NW = 12;
#pragma unroll
    for (int l = 0; l < 6; ++l) { seq[2 * l] = Wl[l]; seq[2 * l + 1] = Wl[l] + 16384; }
  } else {
    NW = 6;
#pragma unroll
    for (int l = 0; l < 6; ++l) seq[l] = Wl[l];
  }
  St8 s8;
  issue8(s8, seq[0], tid);
#pragma unroll
  for (int i = 0; i < 4; ++i) {
    int o = (i * 64 + lane) * 8, r = o >> 7, c = o & 127;
    *(bf16x8*)&slabX[r * 136 + c] = *(const bf16x8*)&Xg[(size_t)(grow0 + r) * 128 + c];
  }
  commit8(s8, Wb, tid);
  __syncthreads();
  f32x4 acc[8];
  zero8(acc);
  for (int s = 0; s < NW; ++s) {
    if (s + 1 < NW) issue8(s8, seq[s + 1], tid);
    const int gg = ws ? (s >> 1) : s;
    const int fin = ws ? (s & 1) : 1;
    pass_slab<4>(acc, (gg & 1) ? slabY : slabX, Wb, lane);
    __syncthreads();
    if (s + 1 < NW) commit8(s8, Wb, tid);
    if (fin) {
      if ((gg & 1) == 0) {
#pragma unroll
        for (int nt = 0; nt < 8; ++nt)
#pragma unroll
          for (int r = 0; r < 4; ++r)
            slabY[(g * 4 + r) * 136 + nt * 16 + rc] = (bf16_t)siluf(acc[nt][r]);
      } else {
#pragma unroll
        for (int nt = 0; nt < 8; ++nt)
#pragma unroll
          for (int r = 0; r < 4; ++r) {
            int ix = (g * 4 + r) * 136 + nt * 16 + rc;
            float v = ((float)slabX[ix] + siluf(acc[nt][r])) * INV_SQRT_2;
            if (gg == 1)
              v = (ldsc(mst, ws, (size_t)(grow0 + g * 4 + r) * 128 + nt * 16 + rc) + v) *
                  INV_SQRT_2;
            slabX[ix] = (bf16_t)v;
          }
      }
      zero8(acc);
    }
    if (s + 1 < NW) __syncthreads();
  }
#pragma unroll
  for (int i = 0; i < 4; ++i) {
    int o = (i * 64 + lane) * 8, r = o >> 7, c = o & 127;
    *(bf16x8*)&outg[(size_t)(grow0 + r) * 128 + c] = *(const bf16x8*)&slabX[r * 136 + c];
  }
}

// ---- resN: 2-layer residual stack in place; 64 rows/block ----
__global__ __launch_bounds__(256, 2) void k_resN2(const int* __restrict__ flag,
    bf16_t* __restrict__ Xg, const bf16_t* W0, const bf16_t* W1,
    const bf16_t* W2, const bf16_t* W3) {
  const int ws = *flag;
  __shared__ __align__(16) bf16_t Xs[64 * 136];
  __shared__ __align__(16) bf16_t Ys[64 * 136];
  __shared__ __align__(16) bf16_t Wb[16384];
  const int tid = threadIdx.x;
  const int lane = tid & 63, wid = tid >> 6;
  const int grow0 = blockIdx.x * 64 + wid * 16;
  const int rc = lane & 15, g = lane >> 4;
  bf16_t* slabX = Xs + wid * (16 * 136);
  bf16_t* slabY = Ys + wid * (16 * 136);
  const bf16_t* Wl[4] = {W0, W1, W2, W3};
  const bf16_t* seq[8];
  int NW;
  if (ws) {
    NW = 8;
#pragma unroll
    for (int l = 0; l < 4; ++l) { seq[2 * l] = Wl[l]; seq[2 * l + 1] = Wl[l] + 16384; }
  } else {
    NW = 4;
#pragma unroll
    for (int l = 0; l < 4; ++l) seq[l] = Wl[l];
  }
  St8 s8;
  issue8(s8, seq[0], tid);
#pragma unroll
  for (int i = 0; i < 4; ++i) {
    int o = (i * 64 + lane) * 8, r = o >> 7, c = o & 127;
    *(bf16x8*)&slabX[r * 136 + c] = *(const bf16x8*)&Xg[(size_t)(grow0 + r) * 128 + c];
  }
  commit8(s8, Wb, tid);
  __syncthreads();
  f32x4 acc[8];
  zero8(acc);
  for (int s = 0; s < NW; ++s) {
    if (s + 1 < NW) issue8(s8, seq[s + 1], tid);
    const int gg = ws ? (s >> 1) : s;
    const int fin = ws ? (s & 1) : 1;
    pass_slab<4>(acc, (gg & 1) ? slabY : slabX, Wb, lane);
    __syncthreads();
    if (s + 1 < NW) commit8(s8, Wb, tid);
    if (fin) {
      if ((gg & 1) == 0) {
#pragma unroll
        for (int nt = 0; nt < 8; ++nt)
#pragma unroll
          for (int r = 0; r < 4; ++r)
            slabY[(g * 4 + r) * 136 + nt * 16 + rc] = (bf16_t)siluf(acc[nt][r]);
      } else {
#pragma unroll
        for (int nt = 0; nt < 8; ++nt)
#pragma unroll
          for (int r = 0; r < 4; ++r) {
            int ix = (g * 4 + r) * 136 + nt * 16 + rc;
            slabX[ix] = (bf16_t)(((float)slabX[ix] + siluf(acc[nt][r])) * INV_SQRT_2);
          }
      }
      zero8(acc);
    }
    if (s + 1 < NW) __syncthreads();
  }
#pragma unroll
  for (int i = 0; i < 4; ++i) {
    int o = (i * 64 + lane) * 8, r = o >> 7, c = o & 127;
    *(bf16x8*)&Xg[(size_t)(grow0 + r) * 128 + c] = *(const bf16x8*)&slabX[r * 136 + c];
  }
}

// ---- ASI(K=384 gathered) + res_m + final combine; 64 rows/block ----
__global__ __launch_bounds__(256, 2) void k_asi2(const int* __restrict__ flag,
    const bf16_t* __restrict__ hnew, const bf16_t* __restrict__ m,
    const int* __restrict__ idx_s, const int* __restrict__ idx_t,
    const bf16_t* Wasi, const bf16_t* Wm0, const bf16_t* Wm1,
    void* __restrict__ outm, int eoff) {
  const int ws = *flag;
  __shared__ __align__(16) bf16_t Xs[64 * 136];
  __shared__ __align__(16) bf16_t Ys[64 * 136];
  __shared__ __align__(16) bf16_t Wb[16384];
  const int tid = threadIdx.x;
  const int lane = tid & 63, wid = tid >> 6;
  const int grow0 = blockIdx.x * 64 + wid * 16;
  const int rc = lane & 15, g = lane >> 4;
  bf16_t* slabX = Xs + wid * (16 * 136);
  bf16_t* slabY = Ys + wid * (16 * 136);
  const int e = grow0 + rc;
  const int rs = idx_s[e], rt = idx_t[e];
  const bf16_t* seq[10];
  int NW;
  if (ws) {
    NW = 10;
    seq[0] = Wasi;         seq[1] = Wasi + 49152;
    seq[2] = Wasi + 16384; seq[3] = Wasi + 65536;
    seq[4] = Wasi + 32768; seq[5] = Wasi + 81920;
    seq[6] = Wm0;          seq[7] = Wm0 + 16384;
    seq[8] = Wm1;          seq[9] = Wm1 + 16384;
  } else {
    NW = 5;
    seq[0] = Wasi; seq[1] = Wasi + 16384; seq[2] = Wasi + 32768;
    seq[3] = Wm0;  seq[4] = Wm1;
  }
  St8 s8;
  issue8(s8, seq[0], tid);
  commit8(s8, Wb, tid);
  __syncthreads();
  f32x4 acc[8];
  zero8(acc);
  bf16x8 af[4];
  for (int s = 0; s < NW; ++s) {
    if (s + 1 < NW) issue8(s8, seq[s + 1], tid);
    const int lg = ws ? (s >> 1) : s;
    const int first = ws ? !(s & 1) : 1;
    const int fin = ws ? (s & 1) : 1;
    if (lg <= 2) {
      if (first) {
        const bf16_t* asrc = (lg == 0) ? hnew + (size_t)rs * 128
                           : (lg == 1) ? hnew + (size_t)rt * 128
                                       : m + (size_t)e * 128;
#pragma unroll
        for (int ks = 0; ks < 4; ++ks) af[ks] = ld8(asrc + ks * 32 + (g << 3));
      }
      pass_glob<4, 8>(acc, af, Wb, lane);
    } else if (lg == 3) {
      pass_slab<4>(acc, slabX, Wb, lane);
    } else {
      pass_slab<4>(acc, slabY, Wb, lane);
    }
    __syncthreads();
    if (s + 1 < NW) commit8(s8, Wb, tid);
    if (fin) {
      if (lg == 2) {
#pragma unroll
        for (int nt = 0; nt < 8; ++nt)
#pragma unroll
          for (int r = 0; r < 4; ++r)
            slabX[(g * 4 + r) * 136 + nt * 16 + rc] = (bf16_t)siluf(acc[nt][r]);
        zero8(acc);
      } else if (lg == 3) {
#pragma unroll
        for (int nt = 0; nt < 8; ++nt)
#pragma unroll
          for (int r = 0; r < 4; ++r)
            slabY[(g * 4 + r) * 136 + nt * 16 + rc] = (bf16_t)siluf(acc[nt][r]);
        zero8(acc);
      } else if (lg == 4) {
#pragma unroll
        for (int nt = 0; nt < 8; ++nt)
#pragma unroll
          for (int r = 0; r < 4; ++r) {
            int row = grow0 + g * 4 + r, col = nt * 16 + rc;
            float x = (float)slabX[(g * 4 + r) * 136 + col];
            float v = (x + siluf(acc[nt][r])) * INV_SQRT_2;
            float res = (toF(m[(size_t)row * 128 + col]) + v) * INV_SQRT_2;
            size_t oi = (size_t)eoff + (size_t)row * 128 + col;
            if (ws) ((float*)outm)[oi] = res;
            else    ((bf16_t*)outm)[oi] = (bf16_t)res;
          }
      }
    }
    if (s + 1 < NW) __syncthreads();
  }
}

// ---- atom embedding scatter ----
__global__ void k_scatter(const int* __restrict__ flag, const bf16_t* __restrict__ m,
                          const void* __restrict__ rbf_h, const void* __restrict__ Wrbf,
                          const int* __restrict__ idx_t, float* __restrict__ h2) {
  const int ws = *flag;
  int e = blockIdx.x;
  int c = threadIdx.x;
  float gt = 0.f;
  if (ws) {
    const float* rh = (const float*)rbf_h + (size_t)e * 16;
    const float* w = (const float*)Wrbf;
#pragma unroll
    for (int k = 0; k < 16; ++k) gt += rh[k] * w[k * 128 + c];
  } else {
    const bf16_t* rh = (const bf16_t*)rbf_h + (size_t)e * 16;
    const bf16_t* w = (const bf16_t*)Wrbf;
#pragma unroll
    for (int k = 0; k < 16; ++k) gt += toF(rh[k]) * toF(w[k * 128 + c]);
  }
  atomicAdd(&h2[(size_t)idx_t[e] * 128 + c], toF(m[(size_t)e * 128 + c]) * gt);
}

// ---- h_new = (h + X)*r2 -> out and X (bf16, for ASI) ----
__global__ void k_hnew(const int* __restrict__ flag, const void* __restrict__ h,
                       bf16_t* __restrict__ X, void* __restrict__ out, int n) {
  const int ws = *flag;
  int i = blockIdx.x * blockDim.x + threadIdx.x;
  if (i >= n) return;
  float v = (ldsc(h, ws, i) + toF(X[i])) * INV_SQRT_2;
  X[i] = (bf16_t)v;
  if (ws) ((float*)out)[i] = v;
  else    ((bf16_t*)out)[i] = (bf16_t)v;
}

// ================================================================================
extern "C" void kernel_launch(void* const* d_in, const int* in_sizes, int n_in,
                              void* d_out, int out_size, void* d_ws, size_t ws_size,
                              hipStream_t stream) {
  const int D = 128;
  const int N = in_sizes[0] / D;   // 8000
  const int E = in_sizes[1] / D;   // 80000

  // workspace: Wpack (1,916,928 B) + 32KB staging-overread pad | flag | 4 slots E*64 bf16
  char* base = (char*)d_ws;
  bf16_t* Wpack = (bf16_t*)base;
  int* flag = (int*)(base + 1916928 + 32768);
  char* dyn = base + 1916928 + 32768 + 256;
  size_t U = (size_t)E * 64 * sizeof(bf16_t);
  bf16_t* s0 = (bf16_t*)dyn;
  bf16_t* s1 = (bf16_t*)(dyn + U);
  bf16_t* s2 = (bf16_t*)(dyn + 2 * U);
  bf16_t* s3 = (bf16_t*)(dyn + 3 * U);
  float* h2 = (float*)(dyn + 2 * U);   // reuses X region (dead by then)
  bf16_t* Rn2 = (bf16_t*)((char*)h2 + (size_t)N * 128 * sizeof(float));

  k_detect<<<1, 64, 0, stream>>>((const unsigned short*)d_in[2], flag);

  // ---- repack table: {input idx, source row-offset, K, Np, Kpad, bilin} ----
  struct Def { int idx; int Krows; int K, Np, Kpad, bilin; };
  const Def defs[25] = {
      {23, 0, 128, 64, 128, 0},    // 0  Qd
      {17, 0, 128, 128, 128, 0},   // 1  Mkt
      {18, 0, 16, 128, 32, 0},     // 2  Rbf
      {19, 0, 128, 64, 128, 0},    // 3  Td
      {21, 0, 64, 128, 64, 0},     // 4  Tst
      {22, 0, 64, 128, 64, 0},     // 5  Tts
      {25, 0, 64, 128, 64, 0},     // 6  Qst
      {26, 0, 64, 128, 64, 0},     // 7  Qts
      {16, 0, 128, 128, 128, 0},   // 8  Sk
      {27, 0, 128, 128, 128, 0},   // 9  B0
      {27, 128, 128, 128, 128, 0}, // 10 B1
      {28, 0, 128, 128, 128, 0},   // 11 A0
      {28, 128, 128, 128, 128, 0}, // 12 A1
      {28, 256, 128, 128, 128, 0}, // 13 A2
      {28, 384, 128, 128, 128, 0}, // 14 A3
      {29, 0, 128, 128, 128, 0},   // 15 M0
      {29, 128, 128, 128, 128, 0}, // 16 M1
      {31, 0, 128, 128, 128, 0},   // 17 Aed
      {32, 0, 128, 128, 128, 0},   // 18 Ae0
      {32, 128, 128, 128, 128, 0}, // 19 Ae1
      {32, 256, 128, 128, 128, 0}, // 20 Ae2
      {32, 384, 128, 128, 128, 0}, // 21 Ae3
      {33, 0, 384, 128, 384, 0},   // 22 Asi
      {20, 0, 1024, 64, 1024, 1},  // 23 Tc (bilinear)
      {24, 0, 1024, 64, 1024, 1},  // 24 Qc (bilinear)
  };
  RTable tab;
  int off[25];
  int cur = 0;
  for (int i = 0; i < 25; ++i) {
    off[i] = cur;
    tab.d[i].src = d_in[defs[i].idx];
    tab.d[i].K = defs[i].K;
    tab.d[i].N = defs[i].Np;
    tab.d[i].Kpad = defs[i].Kpad;
    tab.d[i].dstoff = cur;
    tab.d[i].mode = (defs[i].Krows << 1) | defs[i].bilin;
    cur += 2 * defs[i].Kpad * defs[i].Np;
  }

  k_repack<<<dim3(256, 25), 256, 0, stream>>>(flag, tab, Wpack);

  bf16_t* mkt_tmp = s0;  // spans s0+s1 (E x 128)
  bf16_t* m_kt = s2;
  bf16_t* m_d  = s3;
  bf16_t* xt = s0;
  bf16_t* xq = s1;
  bf16_t* X  = s2;       // spans s2+s3 (E x 128)
  bf16_t* R2 = s0;       // spans s0+s1 (E x 128)

  const int gE64 = E / 64;   // 1250
  const int gN64 = N / 64;   // 125

  k_mkt2<<<gE64, 256, 0, stream>>>(flag, d_in[1], d_in[3], Wpack + off[1], Wpack + off[2],
                                   mkt_tmp);
  k_gemmE2<<<gE64, 256, 0, stream>>>(flag, 0, mkt_tmp, Wpack + off[3], m_kt);
  k_gemmE2<<<gE64, 256, 0, stream>>>(flag, 1, d_in[1], Wpack + off[0], m_d);
  k_bil<<<E / 16, 256, 0, stream>>>(flag, d_in[4], m_kt, (const int*)d_in[9], Wpack + off[23],
                                    xt);
  k_bil<<<E / 16, 256, 0, stream>>>(flag, d_in[5], m_d, (const int*)d_in[12], Wpack + off[24],
                                    xq);
  k_comb2<<<gE64, 256, 0, stream>>>(flag, d_in[1], xt, xq, (const int*)d_in[8],
      Wpack + off[8], Wpack + off[4], Wpack + off[5], Wpack + off[6], Wpack + off[7], X);
  k_resE2<<<gE64, 256, 0, stream>>>(flag, X, d_in[1], Wpack + off[9], Wpack + off[10],
      Wpack + off[11], Wpack + off[12], Wpack + off[13], Wpack + off[14], R2);
  k_zero<<<(N * 128 + 255) / 256, 256, 0, stream>>>(h2, N * 128);
  k_scatter<<<E, 128, 0, stream>>>(flag, R2, d_in[2], d_in[30], (const int*)d_in[7], h2);
  k_gemmN2<<<gN64, 256, 0, stream>>>(flag, h2, Wpack + off[17], Rn2);
  k_resN2<<<gN64, 256, 0, stream>>>(flag, Rn2, Wpack + off[18], Wpack + off[19],
                                    Wpack + off[20], Wpack + off[21]);
  k_hnew<<<(N * 128 + 255) / 256, 256, 0, stream>>>(flag, d_in[0], Rn2, d_out, N * 128);
  k_asi2<<<gE64, 256, 0, stream>>>(flag, Rn2, R2, (const int*)d_in[6], (const int*)d_in[7],
      Wpack + off[22], Wpack + off[15], Wpack + off[16], d_out, N * 128);
}

// Round 7
// 685.484 us; speedup vs baseline: 1.0817x; 1.0817x over previous
//
#include <hip/hip_runtime.h>

#define INV_SQRT_2 0.70710678118654752440f
#define INV_SQRT_3 0.57735026918962576451f

typedef __bf16 bf16_t;
typedef __bf16 bf16x8 __attribute__((ext_vector_type(8)));
typedef __bf16 bf16x4 __attribute__((ext_vector_type(4)));
typedef float f32x4 __attribute__((ext_vector_type(4)));

__device__ __forceinline__ float toF(float x) { return x; }
__device__ __forceinline__ float toF(bf16_t x) { return (float)x; }
// silu via v_rcp_f32 (1-ulp approx; div would emit the full div_fixup sequence)
__device__ __forceinline__ float siluf(float x) {
  return x * __builtin_amdgcn_rcpf(1.f + __expf(-x));
}

__device__ __forceinline__ bf16x8 ld8(const bf16_t* p) { return *(const bf16x8*)p; }
__device__ __forceinline__ bf16x8 ld8(const float* p) {
  bf16x8 r;
#pragma unroll
  for (int j = 0; j < 8; ++j) r[j] = (bf16_t)p[j];
  return r;
}

// runtime-dtype scalar load
__device__ __forceinline__ float ldsc(const void* p, int f32, size_t i) {
  return f32 ? ((const float*)p)[i] : toF(((const bf16_t*)p)[i]);
}

__device__ __forceinline__ f32x4 MFMA(bf16x8 a, bf16x8 b, f32x4 c) {
  return __builtin_amdgcn_mfma_f32_16x16x32_bf16(a, b, c, 0, 0, 0);
}

__device__ __forceinline__ void zero8(f32x4 (&a)[8]) {
#pragma unroll
  for (int i = 0; i < 8; ++i)
#pragma unroll
    for (int q = 0; q < 4; ++q) a[i][q] = 0.f;
}
__device__ __forceinline__ void zero4(f32x4 (&a)[4]) {
#pragma unroll
  for (int i = 0; i < 4; ++i)
#pragma unroll
    for (int q = 0; q < 4; ++q) a[i][q] = 0.f;
}

// Packed-B fragment: element j of lane l = B[ks*32 + (l>>4)*8 + j][nt*16 + (l&15)]
__device__ __forceinline__ bf16x8 ldB(const bf16_t* Bp, int ks, int nt, int NT, int lane) {
  return *(const bf16x8*)(Bp + ((((size_t)ks * NT + nt) * 64 + lane) << 3));
}

// A-fragment loader: 4 chunks of 8, row stride 128, runtime dtype
__device__ __forceinline__ void ldA(bf16x8 (&af)[4], const void* p, int f32, size_t row, int g) {
  if (f32) {
    const float* q = (const float*)p + row * 128 + (g << 3);
#pragma unroll
    for (int ks = 0; ks < 4; ++ks) af[ks] = ld8(q + ks * 32);
  } else {
    const bf16_t* q = (const bf16_t*)p + row * 128 + (g << 3);
#pragma unroll
    for (int ks = 0; ks < 4; ++ks) af[ks] = ld8(q + ks * 32);
  }
}

// ---- weight staging, 512-thread blocks: 32 KB via 4 chunks of 16 B ----
struct Sw4 { bf16x8 v[4]; };
__device__ __forceinline__ void issue512(Sw4& r, const bf16_t* src, int tid) {
#pragma unroll
  for (int i = 0; i < 4; ++i) r.v[i] = *(const bf16x8*)(src + ((i * 512 + tid) << 3));
}
__device__ __forceinline__ void commit512(const Sw4& r, bf16_t* dst, int tid) {
#pragma unroll
  for (int i = 0; i < 4; ++i) *(bf16x8*)&dst[(i * 512 + tid) << 3] = r.v[i];
}
// ---- weight staging, 256-thread blocks: 16 KB via 4 chunks ----
struct St4 { bf16x8 v[4]; };
__device__ __forceinline__ void issue256(St4& r, const bf16_t* src, int tid) {
#pragma unroll
  for (int i = 0; i < 4; ++i) r.v[i] = *(const bf16x8*)(src + ((i * 256 + tid) << 3));
}
__device__ __forceinline__ void commit256(const St4& r, bf16_t* dst, int tid) {
#pragma unroll
  for (int i = 0; i < 4; ++i) *(bf16x8*)&dst[(i * 256 + tid) << 3] = r.v[i];
}

// ---- MFMA pass over 16 rows from A-frag regs; B from LDS ----
template <int KS, int NT>
__device__ __forceinline__ void pass_glob(f32x4 (&acc)[NT], const bf16x8* af,
                                          const bf16_t* Wbuf, int lane) {
#pragma unroll
  for (int ks = 0; ks < KS; ++ks)
#pragma unroll
    for (int nt = 0; nt < NT; ++nt)
      acc[nt] = MFMA(af[ks], *(const bf16x8*)&Wbuf[((ks * NT + nt) * 64 + lane) << 3], acc[nt]);
}
// ---- MFMA pass; A from a 16-row LDS slab (stride 136), B from LDS ----
template <int KS>
__device__ __forceinline__ void pass_slab(f32x4 (&acc)[8], const bf16_t* slab,
                                          const bf16_t* Wbuf, int lane) {
  const int rc = lane & 15, g = lane >> 4;
#pragma unroll
  for (int ks = 0; ks < KS; ++ks) {
    bf16x8 a = *(const bf16x8*)&slab[rc * 136 + ks * 32 + (g << 3)];
#pragma unroll
    for (int nt = 0; nt < 8; ++nt)
      acc[nt] = MFMA(a, *(const bf16x8*)&Wbuf[((ks * 8 + nt) * 64 + lane) << 3], acc[nt]);
  }
}

// ---- dtype detector: probe rbf_h (uniform [0,1]) interpreted as bf16 words ----
__global__ void k_detect(const unsigned short* __restrict__ probe, int* __restrict__ flag) {
  __shared__ int cnt;
  if (threadIdx.x == 0) cnt = 0;
  __syncthreads();
  int bad = 0;
  for (int i = threadIdx.x; i < 256; i += 64) {
    unsigned int u = (unsigned int)probe[i] << 16;
    float v = __uint_as_float(u);
    if (!(v == v) || fabsf(v) > 4.f || v < -0.25f) bad++;
  }
  atomicAdd(&cnt, bad);
  __syncthreads();
  if (threadIdx.x == 0) *flag = (cnt > 16) ? 1 : 0;
}

__global__ void k_zero(float* __restrict__ p, int n) {
  int i = blockIdx.x * blockDim.x + threadIdx.x;
  if (i < n) p[i] = 0.f;
}

// ---------------- weight repack: W(KxN) -> fragment-linear [hi|lo] ----------------
// mode = (Koff << 1) | bilinear.
struct RDesc { const void* src; int K, N, Kpad, dstoff, mode; };
struct RTable { RDesc d[25]; };

__global__ void k_repack(const int* __restrict__ flag, RTable tab, bf16_t* __restrict__ out) {
  const int ws = *flag;
  RDesc d = tab.d[blockIdx.y];
  int p = blockIdx.x * 256 + threadIdx.x;
  int sz = d.Kpad * d.N;
  if (p >= sz) return;
  const int bilin = d.mode & 1;
  const int Koff = d.mode >> 1;
  int NT = d.N >> 4;
  int j = p & 7;
  int lane = (p >> 3) & 63;
  int q = p >> 9;
  int nt = q % NT, ks = q / NT;
  int k = ks * 32 + ((lane >> 4) << 3) + j;
  int col = nt * 16 + (lane & 15);
  size_t si = bilin ? ((size_t)(k & 63) * 16 + (k >> 6)) * 64 + col
                    : (size_t)(k + Koff) * d.N + col;
  float v = (k < d.K) ? ldsc(d.src, ws, si) : 0.f;
  bf16_t hi = (bf16_t)v;
  out[d.dstoff + p] = hi;
  out[d.dstoff + sz + p] = (bf16_t)(v - (float)hi);
}

// ---- MFMA bilinear: 16 edges/block, 256 threads ----
__global__ __launch_bounds__(256) void k_bil(const int* __restrict__ flag,
    const void* __restrict__ basis, const bf16_t* __restrict__ msrc,
    const int* __restrict__ gidx, const bf16_t* __restrict__ Wc,
    bf16_t* __restrict__ out) {
  const int ws = *flag;
  __shared__ __align__(16) bf16_t Ms[96 * 72];
  __shared__ __align__(16) float Bas[16 * 100];
  __shared__ __align__(16) bf16_t P[16384];
  const int tid = threadIdx.x;
  const int e0 = blockIdx.x * 16;
#pragma unroll
  for (int it = 0; it < 3; ++it) {
    int c = tid + it * 256;
    int j = c >> 3, part = c & 7;
    int row = gidx[e0 * 6 + j];
    *(bf16x8*)&Ms[j * 72 + part * 8] = ld8(msrc + (size_t)row * 64 + part * 8);
  }
#pragma unroll
  for (int it = 0; it < 6; ++it) {
    int c = tid + it * 256;
    Bas[(c / 96) * 100 + (c % 96)] = ldsc(basis, ws, (size_t)e0 * 96 + c);
  }
  __syncthreads();
  {
    const int e = tid >> 4, sub = tid & 15, i0 = sub * 4;
    float acc[16][4];
#pragma unroll
    for (int b = 0; b < 16; ++b)
#pragma unroll
      for (int j = 0; j < 4; ++j) acc[b][j] = 0.f;
#pragma unroll
    for (int k = 0; k < 6; ++k) {
      bf16x4 mv = *(const bf16x4*)&Ms[(e * 6 + k) * 72 + i0];
      float mf[4];
#pragma unroll
      for (int j = 0; j < 4; ++j) mf[j] = (float)mv[j];
      const float* bp = &Bas[e * 100 + k * 16];
#pragma unroll
      for (int b4 = 0; b4 < 4; ++b4) {
        f32x4 bv = *(const f32x4*)&bp[b4 * 4];
#pragma unroll
        for (int bb = 0; bb < 4; ++bb)
#pragma unroll
          for (int j = 0; j < 4; ++j) acc[b4 * 4 + bb][j] += bv[bb] * mf[j];
      }
    }
#pragma unroll
    for (int b = 0; b < 16; ++b) {
      int kk = b * 64 + i0;
      int ks = kk >> 5, r5 = kk & 31;
      int lane_hi = r5 >> 3, jj = r5 & 7;
      bf16x4 w;
#pragma unroll
      for (int j = 0; j < 4; ++j) w[j] = (bf16_t)acc[b][j];
      *(bf16x4*)&P[ks * 512 + lane_hi * 128 + e * 8 + jj] = w;
    }
  }
  __syncthreads();
  const int lane = tid & 63, wid = tid >> 6;
  const int rc = lane & 15, g = lane >> 4;
  f32x4 oa[4];
  zero4(oa);
  if (ws) {
#pragma unroll
    for (int k4 = 0; k4 < 8; ++k4)
#pragma unroll
      for (int j = 0; j < 4; ++j) {
        int ks = k4 * 4 + j;
        bf16x8 a = *(const bf16x8*)&P[ks * 512 + lane * 8];
        oa[j] = MFMA(a, ldB(Wc, ks, wid, 4, lane), oa[j]);
        oa[j] = MFMA(a, ldB(Wc + 65536, ks, wid, 4, lane), oa[j]);
      }
  } else {
#pragma unroll
    for (int k4 = 0; k4 < 8; ++k4)
#pragma unroll
      for (int j = 0; j < 4; ++j) {
        int ks = k4 * 4 + j;
        bf16x8 a = *(const bf16x8*)&P[ks * 512 + lane * 8];
        oa[j] = MFMA(a, ldB(Wc, ks, wid, 4, lane), oa[j]);
      }
  }
  f32x4 oacc = (oa[0] + oa[1]) + (oa[2] + oa[3]);
  bf16_t* op = out + ((size_t)e0 + g * 4) * 64 + wid * 16 + rc;
#pragma unroll
  for (int r = 0; r < 4; ++r) op[(size_t)r * 64] = (bf16_t)oacc[r];
}

// ---- m_kt pre: silu(m_st@Wm) * (rbf3@Wr); 128 rows/block, 512 threads ----
__global__ __launch_bounds__(512, 2) void k_mkt2(const int* __restrict__ flag,
    const void* __restrict__ mst, const void* __restrict__ rbf3,
    const bf16_t* __restrict__ Wm, const bf16_t* __restrict__ Wr,
    bf16_t* __restrict__ out) {
  const int ws = *flag;
  __shared__ __align__(16) bf16_t Wb[2][16384];
  __shared__ __align__(16) bf16_t Wrl[8192];
  const int tid = threadIdx.x;
  const int lane = tid & 63, wid = tid >> 6;
  const int grow0 = blockIdx.x * 128 + wid * 16;
  const int rc = lane & 15, g = lane >> 4;
  Sw4 s4;
  issue512(s4, Wm, tid);
  bf16x8 wr0 = *(const bf16x8*)(Wr + (tid << 3));
  bf16x8 wr1 = *(const bf16x8*)(Wr + 4096 + (tid << 3));
  commit512(s4, Wb[0], tid);
  *(bf16x8*)&Wrl[tid << 3] = wr0;
  *(bf16x8*)&Wrl[4096 + (tid << 3)] = wr1;
  __syncthreads();
  bf16x8 af[4];
  ldA(af, mst, ws, (size_t)(grow0 + rc), g);
  bf16x8 az;
#pragma unroll
  for (int j = 0; j < 8; ++j) az[j] = (bf16_t)0.f;
  if (g < 2) {
    if (ws) az = ld8((const float*)rbf3 + (size_t)(grow0 + rc) * 16 + (g << 3));
    else    az = ld8((const bf16_t*)rbf3 + (size_t)(grow0 + rc) * 16 + (g << 3));
  }
  f32x4 ag[8];
  zero8(ag);
#pragma unroll
  for (int nt = 0; nt < 8; ++nt) {
    ag[nt] = MFMA(az, *(const bf16x8*)&Wrl[(nt * 64 + lane) << 3], ag[nt]);
    if (ws) ag[nt] = MFMA(az, *(const bf16x8*)&Wrl[4096 + ((nt * 64 + lane) << 3)], ag[nt]);
  }
  f32x4 am[8];
  zero8(am);
  if (ws) issue512(s4, Wm + 16384, tid);
  pass_glob<4, 8>(am, af, Wb[0], lane);
  if (ws) {
    commit512(s4, Wb[1], tid);
    __syncthreads();
    pass_glob<4, 8>(am, af, Wb[1], lane);
  }
  bf16_t* op = out + (size_t)(grow0 + g * 4) * 128 + rc;
#pragma unroll
  for (int nt = 0; nt < 8; ++nt)
#pragma unroll
    for (int r = 0; r < 4; ++r)
      op[(size_t)r * 128 + nt * 16] = (bf16_t)(siluf(am[nt][r]) * ag[nt][r]);
}

// ---- GEMM+silu: A(M x 128) @ W(128 x 64); 64 rows/block, 256 threads ----
__global__ __launch_bounds__(256, 4) void k_gemmE2(const int* __restrict__ flag, int a_rt,
    const void* __restrict__ A, const bf16_t* __restrict__ W, bf16_t* __restrict__ out) {
  const int ws = *flag;
  const int af32 = a_rt & ws;
  __shared__ __align__(16) bf16_t Wb[2][8192];
  const int tid = threadIdx.x;
  const int lane = tid & 63, wid = tid >> 6;
  const int grow0 = blockIdx.x * 64 + wid * 16;
  const int rc = lane & 15, g = lane >> 4;
  St4 s4;
  issue256(s4, W, tid);
  commit256(s4, Wb[0], tid);
  __syncthreads();
  bf16x8 af[4];
  ldA(af, A, af32, (size_t)(grow0 + rc), g);
  f32x4 acc[4];
  zero4(acc);
  if (ws) issue256(s4, W + 8192, tid);
  pass_glob<4, 4>(acc, af, Wb[0], lane);
  if (ws) {
    commit256(s4, Wb[1], tid);
    __syncthreads();
    pass_glob<4, 4>(acc, af, Wb[1], lane);
  }
  bf16_t* op = out + (size_t)(grow0 + g * 4) * 64 + rc;
#pragma unroll
  for (int nt = 0; nt < 4; ++nt)
#pragma unroll
    for (int r = 0; r < 4; ++r) op[(size_t)r * 64 + nt * 16] = (bf16_t)siluf(acc[nt][r]);
}

// ---- GEMM+silu: A(N x 128, f32) @ W(128 x 128); 128 rows/block, partial-safe ----
__global__ __launch_bounds__(512, 2) void k_gemmN2(const int* __restrict__ flag,
    const float* __restrict__ A, const bf16_t* __restrict__ W, bf16_t* __restrict__ out,
    int M) {
  const int ws = *flag;
  __shared__ __align__(16) bf16_t Wb[2][16384];
  const int tid = threadIdx.x;
  const int lane = tid & 63, wid = tid >> 6;
  const int grow0 = blockIdx.x * 128 + wid * 16;
  const bool act = grow0 < M;
  const int rc = lane & 15, g = lane >> 4;
  Sw4 s4;
  issue512(s4, W, tid);
  commit512(s4, Wb[0], tid);
  __syncthreads();
  bf16x8 af[4];
  if (act) {
    const float* q = A + (size_t)(grow0 + rc) * 128 + (g << 3);
#pragma unroll
    for (int ks = 0; ks < 4; ++ks) af[ks] = ld8(q + ks * 32);
  } else {
#pragma unroll
    for (int ks = 0; ks < 4; ++ks)
#pragma unroll
      for (int j = 0; j < 8; ++j) af[ks][j] = (bf16_t)0.f;
  }
  f32x4 acc[8];
  zero8(acc);
  if (ws) issue512(s4, W + 16384, tid);
  pass_glob<4, 8>(acc, af, Wb[0], lane);
  if (ws) {
    commit512(s4, Wb[1], tid);
    __syncthreads();
    pass_glob<4, 8>(acc, af, Wb[1], lane);
  }
  if (act) {
    bf16_t* op = out + (size_t)(grow0 + g * 4) * 128 + rc;
#pragma unroll
    for (int nt = 0; nt < 8; ++nt)
#pragma unroll
      for (int r = 0; r < 4; ++r) op[(size_t)r * 128 + nt * 16] = (bf16_t)siluf(acc[nt][r]);
  }
}

// ---- combine: 128 rows/block, 512 threads, 5 logical GEMMs, dbuf weights ----
__global__ __launch_bounds__(512, 2) void k_comb2(const int* __restrict__ flag,
    const void* __restrict__ mst, const bf16_t* __restrict__ xt,
    const bf16_t* __restrict__ xq, const int* __restrict__ idx_swap,
    const bf16_t* Wsk, const bf16_t* Wtst, const bf16_t* Wtts,
    const bf16_t* Wqst, const bf16_t* Wqts, bf16_t* __restrict__ X) {
  const int ws = *flag;
  __shared__ __align__(16) bf16_t Wb[2][16384];
  const int tid = threadIdx.x;
  const int lane = tid & 63, wid = tid >> 6;
  const int grow0 = blockIdx.x * 128 + wid * 16;
  const int rc = lane & 15, g = lane >> 4;
  const int arow = grow0 + rc;
  const int srow = idx_swap[arow];
  const bf16_t* wseq[5] = {Wsk, Wtst, Wtts, Wqst, Wqts};
  const int SZs[5] = {16384, 8192, 8192, 8192, 8192};
  Sw4 s4;
  issue512(s4, wseq[0], tid);
  commit512(s4, Wb[0], tid);
  __syncthreads();
  int cur = 0;
  const int NP = ws ? 2 : 1;
  f32x4 total[8], acc[8];
  zero8(acc);
  bf16x8 af[4];
  for (int l = 0; l < 5; ++l) {
    if (l == 0) {
      ldA(af, mst, ws, (size_t)arow, g);
    } else {
      const bf16_t* asrc = (l <= 2) ? xt : xq;
      int r = (l == 1 || l == 3) ? arow : srow;
      af[0] = ld8(asrc + (size_t)r * 64 + (g << 3));
      af[1] = ld8(asrc + (size_t)r * 64 + 32 + (g << 3));
    }
    for (int p = 0; p < NP; ++p) {
      const bool last = (l == 4) && (p == NP - 1);
      if (!last) issue512(s4, (ws && p == 0) ? wseq[l] + SZs[l] : wseq[l + 1], tid);
      if (l == 0) pass_glob<4, 8>(acc, af, Wb[cur], lane);
      else        pass_glob<2, 8>(acc, af, Wb[cur], lane);
      if (!last) {
        commit512(s4, Wb[cur ^ 1], tid);
        __syncthreads();
        cur ^= 1;
      }
    }
    if (l == 0) {
#pragma unroll
      for (int nt = 0; nt < 8; ++nt) total[nt] = acc[nt] * INV_SQRT_3;
    } else {
#pragma unroll
      for (int nt = 0; nt < 8; ++nt)
#pragma unroll
        for (int r = 0; r < 4; ++r)
          total[nt][r] += siluf(acc[nt][r]) * (INV_SQRT_2 * INV_SQRT_3);
    }
    zero8(acc);
  }
  bf16_t* op = X + (size_t)(grow0 + g * 4) * 128 + rc;
#pragma unroll
  for (int nt = 0; nt < 8; ++nt)
#pragma unroll
    for (int r = 0; r < 4; ++r) op[(size_t)r * 128 + nt * 16] = (bf16_t)total[nt][r];
}

// ---- resE: res_before + mst-mix + res_after(2 layers); 128 rows, 512 thr, dbuf ----
__global__ __launch_bounds__(512, 1) void k_resE2(const int* __restrict__ flag,
    const bf16_t* __restrict__ Xg, const void* __restrict__ mst,
    const bf16_t* W0, const bf16_t* W1, const bf16_t* W2,
    const bf16_t* W3, const bf16_t* W4, const bf16_t* W5,
    bf16_t* __restrict__ outg) {
  const int ws = *flag;
  __shared__ __align__(16) bf16_t Xs[128 * 136];
  __shared__ __align__(16) bf16_t Ys[128 * 136];
  __shared__ __align__(16) bf16_t Wb[2][16384];
  const int tid = threadIdx.x;
  const int lane = tid & 63, wid = tid >> 6;
  const int grow0 = blockIdx.x * 128 + wid * 16;
  const int rc = lane & 15, g = lane >> 4;
  bf16_t* slabX = Xs + wid * (16 * 136);
  bf16_t* slabY = Ys + wid * (16 * 136);
  const bf16_t* Wl[6] = {W0, W1, W2, W3, W4, W5};
  const bf16_t* seq[12];
  int NW;
  if (ws) {
    NW = 12;
#pragma unroll
    for (int l = 0; l < 6; ++l) { seq[2 * l] = Wl[l]; seq[2 * l + 1] = Wl[l] + 16384; }
  } else {
    NW = 6;
#pragma unroll
    for (int l = 0; l < 6; ++l) seq[l] = Wl[l];
  }
  Sw4 s4;
  issue512(s4, seq[0], tid);
#pragma unroll
  for (int i = 0; i < 4; ++i) {
    int o = (i * 64 + lane) * 8, r = o >> 7, c = o & 127;
    *(bf16x8*)&slabX[r * 136 + c] = *(const bf16x8*)&Xg[(size_t)(grow0 + r) * 128 + c];
  }
  commit512(s4, Wb[0], tid);
  __syncthreads();
  f32x4 acc[8];
  zero8(acc);
  int cur = 0;
  for (int s = 0; s < NW; ++s) {
    if (s + 1 < NW) issue512(s4, seq[s + 1], tid);
    const int gg = ws ? (s >> 1) : s;
    const int fin = ws ? (s & 1) : 1;
    pass_slab<4>(acc, (gg & 1) ? slabY : slabX, Wb[cur], lane);
    if (fin) {
      if ((gg & 1) == 0) {
#pragma unroll
        for (int nt = 0; nt < 8; ++nt)
#pragma unroll
          for (int r = 0; r < 4; ++r)
            slabY[(g * 4 + r) * 136 + nt * 16 + rc] = (bf16_t)siluf(acc[nt][r]);
      } else {
#pragma unroll
        for (int nt = 0; nt < 8; ++nt)
#pragma unroll
          for (int r = 0; r < 4; ++r) {
            int ix = (g * 4 + r) * 136 + nt * 16 + rc;
            float v = ((float)slabX[ix] + siluf(acc[nt][r])) * INV_SQRT_2;
            if (gg == 1)
              v = (ldsc(mst, ws, (size_t)(grow0 + g * 4 + r) * 128 + nt * 16 + rc) + v) *
                  INV_SQRT_2;
            slabX[ix] = (bf16_t)v;
          }
      }
      zero8(acc);
    }
    if (s + 1 < NW) {
      commit512(s4, Wb[cur ^ 1], tid);
      __syncthreads();
      cur ^= 1;
    }
  }
#pragma unroll
  for (int i = 0; i < 4; ++i) {
    int o = (i * 64 + lane) * 8, r = o >> 7, c = o & 127;
    *(bf16x8*)&outg[(size_t)(grow0 + r) * 128 + c] = *(const bf16x8*)&slabX[r * 136 + c];
  }
}

// ---- resN: 2-layer residual stack in place; 128 rows, 512 thr, partial-safe ----
__global__ __launch_bounds__(512, 1) void k_resN2(const int* __restrict__ flag,
    bf16_t* __restrict__ Xg, const bf16_t* W0, const bf16_t* W1,
    const bf16_t* W2, const bf16_t* W3, int M) {
  const int ws = *flag;
  __shared__ __align__(16) bf16_t Xs[128 * 136];
  __shared__ __align__(16) bf16_t Ys[128 * 136];
  __shared__ __align__(16) bf16_t Wb[2][16384];
  const int tid = threadIdx.x;
  const int lane = tid & 63, wid = tid >> 6;
  const int grow0 = blockIdx.x * 128 + wid * 16;
  const bool act = grow0 < M;
  const int rc = lane & 15, g = lane >> 4;
  bf16_t* slabX = Xs + wid * (16 * 136);
  bf16_t* slabY = Ys + wid * (16 * 136);
  const bf16_t* Wl[4] = {W0, W1, W2, W3};
  const bf16_t* seq[8];
  int NW;
  if (ws) {
    NW = 8;
#pragma unroll
    for (int l = 0; l < 4; ++l) { seq[2 * l] = Wl[l]; seq[2 * l + 1] = Wl[l] + 16384; }
  } else {
    NW = 4;
#pragma unroll
    for (int l = 0; l < 4; ++l) seq[l] = Wl[l];
  }
  Sw4 s4;
  issue512(s4, seq[0], tid);
  if (act) {
#pragma unroll
    for (int i = 0; i < 4; ++i) {
      int o = (i * 64 + lane) * 8, r = o >> 7, c = o & 127;
      *(bf16x8*)&slabX[r * 136 + c] = *(const bf16x8*)&Xg[(size_t)(grow0 + r) * 128 + c];
    }
  }
  commit512(s4, Wb[0], tid);
  __syncthreads();
  f32x4 acc[8];
  zero8(acc);
  int cur = 0;
  for (int s = 0; s < NW; ++s) {
    if (s + 1 < NW) issue512(s4, seq[s + 1], tid);
    const int gg = ws ? (s >> 1) : s;
    const int fin = ws ? (s & 1) : 1;
    pass_slab<4>(acc, (gg & 1) ? slabY : slabX, Wb[cur], lane);
    if (fin) {
      if ((gg & 1) == 0) {
#pragma unroll
        for (int nt = 0; nt < 8; ++nt)
#pragma unroll
          for (int r = 0; r < 4; ++r)
            slabY[(g * 4 + r) * 136 + nt * 16 + rc] = (bf16_t)siluf(acc[nt][r]);
      } else {
#pragma unroll
        for (int nt = 0; nt < 8; ++nt)
#pragma unroll
          for (int r = 0; r < 4; ++r) {
            int ix = (g * 4 + r) * 136 + nt * 16 + rc;
            slabX[ix] = (bf16_t)(((float)slabX[ix] + siluf(acc[nt][r])) * INV_SQRT_2);
          }
      }
      zero8(acc);
    }
    if (s + 1 < NW) {
      commit512(s4, Wb[cur ^ 1], tid);
      __syncthreads();
      cur ^= 1;
    }
  }
  if (act) {
#pragma unroll
    for (int i = 0; i < 4; ++i) {
      int o = (i * 64 + lane) * 8, r = o >> 7, c = o & 127;
      *(bf16x8*)&Xg[(size_t)(grow0 + r) * 128 + c] = *(const bf16x8*)&slabX[r * 136 + c];
    }
  }
}

// ---- ASI(K=384 gathered) + res_m + final combine; 128 rows, 512 thr, dbuf ----
__global__ __launch_bounds__(512, 1) void k_asi2(const int* __restrict__ flag,
    const bf16_t* __restrict__ hnew, const bf16_t* __restrict__ m,
    const int* __restrict__ idx_s, const int* __restrict__ idx_t,
    const bf16_t* Wasi, const bf16_t* Wm0, const bf16_t* Wm1,
    void* __restrict__ outm, int eoff) {
  const int ws = *flag;
  __shared__ __align__(16) bf16_t Xs[128 * 136];
  __shared__ __align__(16) bf16_t Ys[128 * 136];
  __shared__ __align__(16) bf16_t Wb[2][16384];
  const int tid = threadIdx.x;
  const int lane = tid & 63, wid = tid >> 6;
  const int grow0 = blockIdx.x * 128 + wid * 16;
  const int rc = lane & 15, g = lane >> 4;
  bf16_t* slabX = Xs + wid * (16 * 136);
  bf16_t* slabY = Ys + wid * (16 * 136);
  const int e = grow0 + rc;
  const int rs = idx_s[e], rt = idx_t[e];
  const bf16_t* seq[10];
  int NW;
  if (ws) {
    NW = 10;
    seq[0] = Wasi;         seq[1] = Wasi + 49152;
    seq[2] = Wasi + 16384; seq[3] = Wasi + 65536;
    seq[4] = Wasi + 32768; seq[5] = Wasi + 81920;
    seq[6] = Wm0;          seq[7] = Wm0 + 16384;
    seq[8] = Wm1;          seq[9] = Wm1 + 16384;
  } else {
    NW = 5;
    seq[0] = Wasi; seq[1] = Wasi + 16384; seq[2] = Wasi + 32768;
    seq[3] = Wm0;  seq[4] = Wm1;
  }
  Sw4 s4;
  issue512(s4, seq[0], tid);
  commit512(s4, Wb[0], tid);
  __syncthreads();
  f32x4 acc[8];
  zero8(acc);
  bf16x8 af[4];
  int cur = 0;
  for (int s = 0; s < NW; ++s) {
    if (s + 1 < NW) issue512(s4, seq[s + 1], tid);
    const int lg = ws ? (s >> 1) : s;
    const int first = ws ? !(s & 1) : 1;
    const int fin = ws ? (s & 1) : 1;
    if (lg <= 2) {
      if (first) {
        const bf16_t* asrc = (lg == 0) ? hnew + (size_t)rs * 128
                           : (lg == 1) ? hnew + (size_t)rt * 128
                                       : m + (size_t)e * 128;
#pragma unroll
        for (int ks = 0; ks < 4; ++ks) af[ks] = ld8(asrc + ks * 32 + (g << 3));
      }
      pass_glob<4, 8>(acc, af, Wb[cur], lane);
    } else if (lg == 3) {
      pass_slab<4>(acc, slabX, Wb[cur], lane);
    } else {
      pass_slab<4>(acc, slabY, Wb[cur], lane);
    }
    if (fin) {
      if (lg == 2) {
#pragma unroll
        for (int nt = 0; nt < 8; ++nt)
#pragma unroll
          for (int r = 0; r < 4; ++r)
            slabX[(g * 4 + r) * 136 + nt * 16 + rc] = (bf16_t)siluf(acc[nt][r]);
        zero8(acc);
      } else if (lg == 3) {
#pragma unroll
        for (int nt = 0; nt < 8; ++nt)
#pragma unroll
          for (int r = 0; r < 4; ++r)
            slabY[(g * 4 + r) * 136 + nt * 16 + rc] = (bf16_t)siluf(acc[nt][r]);
        zero8(acc);
      } else if (lg == 4) {
#pragma unroll
        for (int nt = 0; nt < 8; ++nt)
#pragma unroll
          for (int r = 0; r < 4; ++r) {
            int row = grow0 + g * 4 + r, col = nt * 16 + rc;
            float x = (float)slabX[(g * 4 + r) * 136 + col];
            float v = (x + siluf(acc[nt][r])) * INV_SQRT_2;
            float res = (toF(m[(size_t)row * 128 + col]) + v) * INV_SQRT_2;
            size_t oi = (size_t)eoff + (size_t)row * 128 + col;
            if (ws) ((float*)outm)[oi] = res;
            else    ((bf16_t*)outm)[oi] = (bf16_t)res;
          }
      }
    }
    if (s + 1 < NW) {
      commit512(s4, Wb[cur ^ 1], tid);
      __syncthreads();
      cur ^= 1;
    }
  }
}

// ---- atom embedding scatter ----
__global__ void k_scatter(const int* __restrict__ flag, const bf16_t* __restrict__ m,
                          const void* __restrict__ rbf_h, const void* __restrict__ Wrbf,
                          const int* __restrict__ idx_t, float* __restrict__ h2) {
  const int ws = *flag;
  int e = blockIdx.x;
  int c = threadIdx.x;
  float gt = 0.f;
  if (ws) {
    const float* rh = (const float*)rbf_h + (size_t)e * 16;
    const float* w = (const float*)Wrbf;
#pragma unroll
    for (int k = 0; k < 16; ++k) gt += rh[k] * w[k * 128 + c];
  } else {
    const bf16_t* rh = (const bf16_t*)rbf_h + (size_t)e * 16;
    const bf16_t* w = (const bf16_t*)Wrbf;
#pragma unroll
    for (int k = 0; k < 16; ++k) gt += toF(rh[k]) * toF(w[k * 128 + c]);
  }
  atomicAdd(&h2[(size_t)idx_t[e] * 128 + c], toF(m[(size_t)e * 128 + c]) * gt);
}

// ---- h_new = (h + X)*r2 -> out and X (bf16, for ASI) ----
__global__ void k_hnew(const int* __restrict__ flag, const void* __restrict__ h,
                       bf16_t* __restrict__ X, void* __restrict__ out, int n) {
  const int ws = *flag;
  int i = blockIdx.x * blockDim.x + threadIdx.x;
  if (i >= n) return;
  float v = (ldsc(h, ws, i) + toF(X[i])) * INV_SQRT_2;
  X[i] = (bf16_t)v;
  if (ws) ((float*)out)[i] = v;
  else    ((bf16_t*)out)[i] = (bf16_t)v;
}

// ================================================================================
extern "C" void kernel_launch(void* const* d_in, const int* in_sizes, int n_in,
                              void* d_out, int out_size, void* d_ws, size_t ws_size,
                              hipStream_t stream) {
  const int D = 128;
  const int N = in_sizes[0] / D;   // 8000
  const int E = in_sizes[1] / D;   // 80000

  // workspace: Wpack (1,916,928 B) + 32KB staging-overread pad | flag | 4 slots E*64 bf16
  char* base = (char*)d_ws;
  bf16_t* Wpack = (bf16_t*)base;
  int* flag = (int*)(base + 1916928 + 32768);
  char* dyn = base + 1916928 + 32768 + 256;
  size_t U = (size_t)E * 64 * sizeof(bf16_t);
  bf16_t* s0 = (bf16_t*)dyn;
  bf16_t* s1 = (bf16_t*)(dyn + U);
  bf16_t* s2 = (bf16_t*)(dyn + 2 * U);
  bf16_t* s3 = (bf16_t*)(dyn + 3 * U);
  float* h2 = (float*)(dyn + 2 * U);   // reuses X region (dead by then)
  bf16_t* Rn2 = (bf16_t*)((char*)h2 + (size_t)N * 128 * sizeof(float));

  k_detect<<<1, 64, 0, stream>>>((const unsigned short*)d_in[2], flag);

  // ---- repack table: {input idx, source row-offset, K, Np, Kpad, bilin} ----
  struct Def { int idx; int Krows; int K, Np, Kpad, bilin; };
  const Def defs[25] = {
      {23, 0, 128, 64, 128, 0},    // 0  Qd
      {17, 0, 128, 128, 128, 0},   // 1  Mkt
      {18, 0, 16, 128, 32, 0},     // 2  Rbf
      {19, 0, 128, 64, 128, 0},    // 3  Td
      {21, 0, 64, 128, 64, 0},     // 4  Tst
      {22, 0, 64, 128, 64, 0},     // 5  Tts
      {25, 0, 64, 128, 64, 0},     // 6  Qst
      {26, 0, 64, 128, 64, 0},     // 7  Qts
      {16, 0, 128, 128, 128, 0},   // 8  Sk
      {27, 0, 128, 128, 128, 0},   // 9  B0
      {27, 128, 128, 128, 128, 0}, // 10 B1
      {28, 0, 128, 128, 128, 0},   // 11 A0
      {28, 128, 128, 128, 128, 0}, // 12 A1
      {28, 256, 128, 128, 128, 0}, // 13 A2
      {28, 384, 128, 128, 128, 0}, // 14 A3
      {29, 0, 128, 128, 128, 0},   // 15 M0
      {29, 128, 128, 128, 128, 0}, // 16 M1
      {31, 0, 128, 128, 128, 0},   // 17 Aed
      {32, 0, 128, 128, 128, 0},   // 18 Ae0
      {32, 128, 128, 128, 128, 0}, // 19 Ae1
      {32, 256, 128, 128, 128, 0}, // 20 Ae2
      {32, 384, 128, 128, 128, 0}, // 21 Ae3
      {33, 0, 384, 128, 384, 0},   // 22 Asi
      {20, 0, 1024, 64, 1024, 1},  // 23 Tc (bilinear)
      {24, 0, 1024, 64, 1024, 1},  // 24 Qc (bilinear)
  };
  RTable tab;
  int off[25];
  int cur = 0;
  for (int i = 0; i < 25; ++i) {
    off[i] = cur;
    tab.d[i].src = d_in[defs[i].idx];
    tab.d[i].K = defs[i].K;
    tab.d[i].N = defs[i].Np;
    tab.d[i].Kpad = defs[i].Kpad;
    tab.d[i].dstoff = cur;
    tab.d[i].mode = (defs[i].Krows << 1) | defs[i].bilin;
    cur += 2 * defs[i].Kpad * defs[i].Np;
  }

  k_repack<<<dim3(256, 25), 256, 0, stream>>>(flag, tab, Wpack);

  bf16_t* mkt_tmp = s0;  // spans s0+s1 (E x 128)
  bf16_t* m_kt = s2;
  bf16_t* m_d  = s3;
  bf16_t* xt = s0;
  bf16_t* xq = s1;
  bf16_t* X  = s2;       // spans s2+s3 (E x 128)
  bf16_t* R2 = s0;       // spans s0+s1 (E x 128)

  const int gE128 = E / 128;            // 625
  const int gE64  = E / 64;             // 1250
  const int gN128 = (N + 127) / 128;    // 63 (partial last block)

  k_mkt2<<<gE128, 512, 0, stream>>>(flag, d_in[1], d_in[3], Wpack + off[1], Wpack + off[2],
                                    mkt_tmp);
  k_gemmE2<<<gE64, 256, 0, stream>>>(flag, 0, mkt_tmp, Wpack + off[3], m_kt);
  k_gemmE2<<<gE64, 256, 0, stream>>>(flag, 1, d_in[1], Wpack + off[0], m_d);
  k_bil<<<E / 16, 256, 0, stream>>>(flag, d_in[4], m_kt, (const int*)d_in[9], Wpack + off[23],
                                    xt);
  k_bil<<<E / 16, 256, 0, stream>>>(flag, d_in[5], m_d, (const int*)d_in[12], Wpack + off[24],
                                    xq);
  k_comb2<<<gE128, 512, 0, stream>>>(flag, d_in[1], xt, xq, (const int*)d_in[8],
      Wpack + off[8], Wpack + off[4], Wpack + off[5], Wpack + off[6], Wpack + off[7], X);
  k_resE2<<<gE128, 512, 0, stream>>>(flag, X, d_in[1], Wpack + off[9], Wpack + off[10],
      Wpack + off[11], Wpack + off[12], Wpack + off[13], Wpack + off[14], R2);
  k_zero<<<(N * 128 + 255) / 256, 256, 0, stream>>>(h2, N * 128);
  k_scatter<<<E, 128, 0, stream>>>(flag, R2, d_in[2], d_in[30], (const int*)d_in[7], h2);
  k_gemmN2<<<gN128, 512, 0, stream>>>(flag, h2, Wpack + off[17], Rn2, N);
  k_resN2<<<gN128, 512, 0, stream>>>(flag, Rn2, Wpack + off[18], Wpack + off[19],
                                     Wpack + off[20], Wpack + off[21], N);
  k_hnew<<<(N * 128 + 255) / 256, 256, 0, stream>>>(flag, d_in[0], Rn2, d_out, N * 128);
  k_asi2<<<gE128, 512, 0, stream>>>(flag, Rn2, R2, (const int*)d_in[6], (const int*)d_in[7],
      Wpack + off[22], Wpack + off[15], Wpack + off[16], d_out, N * 128);
}

// Round 9
// 665.130 us; speedup vs baseline: 1.1148x; 1.0306x over previous
//
#include <hip/hip_runtime.h>

#define INV_SQRT_2 0.70710678118654752440f
#define INV_SQRT_3 0.57735026918962576451f

typedef __bf16 bf16_t;
typedef __bf16 bf16x8 __attribute__((ext_vector_type(8)));
typedef __bf16 bf16x4 __attribute__((ext_vector_type(4)));
typedef float f32x4 __attribute__((ext_vector_type(4)));

__device__ __forceinline__ float toF(float x) { return x; }
__device__ __forceinline__ float toF(bf16_t x) { return (float)x; }
// silu via v_rcp_f32 (1-ulp approx; bf16 output rounding absorbs it)
__device__ __forceinline__ float siluf(float x) {
  return x * __builtin_amdgcn_rcpf(1.f + __expf(-x));
}

__device__ __forceinline__ bf16x8 ld8(const bf16_t* p) { return *(const bf16x8*)p; }
__device__ __forceinline__ bf16x8 ld8(const float* p) {
  bf16x8 r;
#pragma unroll
  for (int j = 0; j < 8; ++j) r[j] = (bf16_t)p[j];
  return r;
}

__device__ __forceinline__ float ldsc(const void* p, int f32, size_t i) {
  return f32 ? ((const float*)p)[i] : toF(((const bf16_t*)p)[i]);
}

__device__ __forceinline__ f32x4 MFMA(bf16x8 a, bf16x8 b, f32x4 c) {
  return __builtin_amdgcn_mfma_f32_16x16x32_bf16(a, b, c, 0, 0, 0);
}

__device__ __forceinline__ void zero8(f32x4 (&a)[8]) {
#pragma unroll
  for (int i = 0; i < 8; ++i)
#pragma unroll
    for (int q = 0; q < 4; ++q) a[i][q] = 0.f;
}
__device__ __forceinline__ void zero4(f32x4 (&a)[4]) {
#pragma unroll
  for (int i = 0; i < 4; ++i)
#pragma unroll
    for (int q = 0; q < 4; ++q) a[i][q] = 0.f;
}

// Packed-B fragment: element j of lane l = B[ks*32 + (l>>4)*8 + j][nt*16 + (l&15)]
__device__ __forceinline__ bf16x8 ldB(const bf16_t* Bp, int ks, int nt, int NT, int lane) {
  return *(const bf16x8*)(Bp + ((((size_t)ks * NT + nt) * 64 + lane) << 3));
}

// A-fragment loader, compile-time dtype
template <bool F32>
__device__ __forceinline__ void ldAt(bf16x8 (&af)[4], const void* p, size_t row, int g) {
  if (F32) {
    const float* q = (const float*)p + row * 128 + (g << 3);
#pragma unroll
    for (int ks = 0; ks < 4; ++ks) af[ks] = ld8(q + ks * 32);
  } else {
    const bf16_t* q = (const bf16_t*)p + row * 128 + (g << 3);
#pragma unroll
    for (int ks = 0; ks < 4; ++ks) af[ks] = ld8(q + ks * 32);
  }
}

// ---- weight staging, 512-thread blocks: 32 KB via 4 chunks of 16 B ----
struct Sw4 { bf16x8 v[4]; };
__device__ __forceinline__ void issue512(Sw4& r, const bf16_t* src, int tid) {
#pragma unroll
  for (int i = 0; i < 4; ++i) r.v[i] = *(const bf16x8*)(src + ((i * 512 + tid) << 3));
}
__device__ __forceinline__ void commit512(const Sw4& r, bf16_t* dst, int tid) {
#pragma unroll
  for (int i = 0; i < 4; ++i) *(bf16x8*)&dst[(i * 512 + tid) << 3] = r.v[i];
}
// ---- weight staging, 256-thread blocks: 16 KB ----
struct St4 { bf16x8 v[4]; };
__device__ __forceinline__ void issue256(St4& r, const bf16_t* src, int tid) {
#pragma unroll
  for (int i = 0; i < 4; ++i) r.v[i] = *(const bf16x8*)(src + ((i * 256 + tid) << 3));
}
__device__ __forceinline__ void commit256(const St4& r, bf16_t* dst, int tid) {
#pragma unroll
  for (int i = 0; i < 4; ++i) *(bf16x8*)&dst[(i * 256 + tid) << 3] = r.v[i];
}

// ---- MFMA pass over 16 rows from A-frag regs; B from LDS ----
template <int KS, int NT>
__device__ __forceinline__ void pass_glob(f32x4 (&acc)[NT], const bf16x8* af,
                                          const bf16_t* Wbuf, int lane) {
#pragma unroll
  for (int ks = 0; ks < KS; ++ks)
#pragma unroll
    for (int nt = 0; nt < NT; ++nt)
      acc[nt] = MFMA(af[ks], *(const bf16x8*)&Wbuf[((ks * NT + nt) * 64 + lane) << 3], acc[nt]);
}
// ---- MFMA pass; A from a 16-row LDS slab (stride 136), B from LDS ----
template <int KS>
__device__ __forceinline__ void pass_slab(f32x4 (&acc)[8], const bf16_t* slab,
                                          const bf16_t* Wbuf, int lane) {
  const int rc = lane & 15, g = lane >> 4;
#pragma unroll
  for (int ks = 0; ks < KS; ++ks) {
    bf16x8 a = *(const bf16x8*)&slab[rc * 136 + ks * 32 + (g << 3)];
#pragma unroll
    for (int nt = 0; nt < 8; ++nt)
      acc[nt] = MFMA(a, *(const bf16x8*)&Wbuf[((ks * 8 + nt) * 64 + lane) << 3], acc[nt]);
  }
}

// ---- dtype detector ----
__global__ void k_detect(const unsigned short* __restrict__ probe, int* __restrict__ flag) {
  __shared__ int cnt;
  if (threadIdx.x == 0) cnt = 0;
  __syncthreads();
  int bad = 0;
  for (int i = threadIdx.x; i < 256; i += 64) {
    unsigned int u = (unsigned int)probe[i] << 16;
    float v = __uint_as_float(u);
    if (!(v == v) || fabsf(v) > 4.f || v < -0.25f) bad++;
  }
  atomicAdd(&cnt, bad);
  __syncthreads();
  if (threadIdx.x == 0) *flag = (cnt > 16) ? 1 : 0;
}

__global__ void k_zero(float* __restrict__ p, int n) {
  int i = blockIdx.x * blockDim.x + threadIdx.x;
  if (i < n) p[i] = 0.f;
}

// ---------------- weight repack: W(KxN) -> fragment-linear [hi|lo] ----------------
struct RDesc { const void* src; int K, N, Kpad, dstoff, mode; };
struct RTable { RDesc d[25]; };

__global__ void k_repack(const int* __restrict__ flag, RTable tab, bf16_t* __restrict__ out) {
  const int ws = *flag;
  RDesc d = tab.d[blockIdx.y];
  int p = blockIdx.x * 256 + threadIdx.x;
  int sz = d.Kpad * d.N;
  if (p >= sz) return;
  const int bilin = d.mode & 1;
  const int Koff = d.mode >> 1;
  int NT = d.N >> 4;
  int j = p & 7;
  int lane = (p >> 3) & 63;
  int q = p >> 9;
  int nt = q % NT, ks = q / NT;
  int k = ks * 32 + ((lane >> 4) << 3) + j;
  int col = nt * 16 + (lane & 15);
  size_t si = bilin ? ((size_t)(k & 63) * 16 + (k >> 6)) * 64 + col
                    : (size_t)(k + Koff) * d.N + col;
  float v = (k < d.K) ? ldsc(d.src, ws, si) : 0.f;
  bf16_t hi = (bf16_t)v;
  out[d.dstoff + p] = hi;
  out[d.dstoff + sz + p] = (bf16_t)(v - (float)hi);
}

// ---- MFMA bilinear: 16 edges/block, 256 threads ----
__global__ __launch_bounds__(256) void k_bil(const int* __restrict__ flag,
    const void* __restrict__ basis, const bf16_t* __restrict__ msrc,
    const int* __restrict__ gidx, const bf16_t* __restrict__ Wc,
    bf16_t* __restrict__ out) {
  const int ws = *flag;
  __shared__ __align__(16) bf16_t Ms[96 * 72];
  __shared__ __align__(16) float Bas[16 * 100];
  __shared__ __align__(16) bf16_t P[16384];
  const int tid = threadIdx.x;
  const int e0 = blockIdx.x * 16;
#pragma unroll
  for (int it = 0; it < 3; ++it) {
    int c = tid + it * 256;
    int j = c >> 3, part = c & 7;
    int row = gidx[e0 * 6 + j];
    *(bf16x8*)&Ms[j * 72 + part * 8] = ld8(msrc + (size_t)row * 64 + part * 8);
  }
#pragma unroll
  for (int it = 0; it < 6; ++it) {
    int c = tid + it * 256;
    Bas[(c / 96) * 100 + (c % 96)] = ldsc(basis, ws, (size_t)e0 * 96 + c);
  }
  __syncthreads();
  {
    const int e = tid >> 4, sub = tid & 15, i0 = sub * 4;
    float acc[16][4];
#pragma unroll
    for (int b = 0; b < 16; ++b)
#pragma unroll
      for (int j = 0; j < 4; ++j) acc[b][j] = 0.f;
#pragma unroll
    for (int k = 0; k < 6; ++k) {
      bf16x4 mv = *(const bf16x4*)&Ms[(e * 6 + k) * 72 + i0];
      float mf[4];
#pragma unroll
      for (int j = 0; j < 4; ++j) mf[j] = (float)mv[j];
      const float* bp = &Bas[e * 100 + k * 16];
#pragma unroll
      for (int b4 = 0; b4 < 4; ++b4) {
        f32x4 bv = *(const f32x4*)&bp[b4 * 4];
#pragma unroll
        for (int bb = 0; bb < 4; ++bb)
#pragma unroll
          for (int j = 0; j < 4; ++j) acc[b4 * 4 + bb][j] += bv[bb] * mf[j];
      }
    }
#pragma unroll
    for (int b = 0; b < 16; ++b) {
      int kk = b * 64 + i0;
      int ks = kk >> 5, r5 = kk & 31;
      int lane_hi = r5 >> 3, jj = r5 & 7;
      bf16x4 w;
#pragma unroll
      for (int j = 0; j < 4; ++j) w[j] = (bf16_t)acc[b][j];
      *(bf16x4*)&P[ks * 512 + lane_hi * 128 + e * 8 + jj] = w;
    }
  }
  __syncthreads();
  const int lane = tid & 63, wid = tid >> 6;
  const int rc = lane & 15, g = lane >> 4;
  f32x4 oa[4];
  zero4(oa);
  if (ws) {
#pragma unroll
    for (int k4 = 0; k4 < 8; ++k4)
#pragma unroll
      for (int j = 0; j < 4; ++j) {
        int ks = k4 * 4 + j;
        bf16x8 a = *(const bf16x8*)&P[ks * 512 + lane * 8];
        oa[j] = MFMA(a, ldB(Wc, ks, wid, 4, lane), oa[j]);
        oa[j] = MFMA(a, ldB(Wc + 65536, ks, wid, 4, lane), oa[j]);
      }
  } else {
#pragma unroll
    for (int k4 = 0; k4 < 8; ++k4)
#pragma unroll
      for (int j = 0; j < 4; ++j) {
        int ks = k4 * 4 + j;
        bf16x8 a = *(const bf16x8*)&P[ks * 512 + lane * 8];
        oa[j] = MFMA(a, ldB(Wc, ks, wid, 4, lane), oa[j]);
      }
  }
  f32x4 oacc = (oa[0] + oa[1]) + (oa[2] + oa[3]);
  bf16_t* op = out + ((size_t)e0 + g * 4) * 64 + wid * 16 + rc;
#pragma unroll
  for (int r = 0; r < 4; ++r) op[(size_t)r * 64] = (bf16_t)oacc[r];
}

// ================= templated bodies (compile-time WS) =================

// ---- m_kt body ----
template <bool WS>
__device__ __forceinline__ void mkt_body(bf16_t* Wb, bf16_t* Wrl,
    const void* mst, const void* rbf3, const bf16_t* Wm, const bf16_t* Wr,
    bf16_t* out, int tid, int bx) {
  const int lane = tid & 63, wid = tid >> 6;
  const int grow0 = bx * 128 + wid * 16;
  const int rc = lane & 15, g = lane >> 4;
  Sw4 s4;
  issue512(s4, Wm, tid);
  bf16x8 wr0 = *(const bf16x8*)(Wr + (tid << 3));
  bf16x8 wr1 = *(const bf16x8*)(Wr + 4096 + (tid << 3));
  commit512(s4, Wb, tid);
  *(bf16x8*)&Wrl[tid << 3] = wr0;
  *(bf16x8*)&Wrl[4096 + (tid << 3)] = wr1;
  __syncthreads();
  bf16x8 af[4];
  ldAt<WS>(af, mst, (size_t)(grow0 + rc), g);
  bf16x8 az;
#pragma unroll
  for (int j = 0; j < 8; ++j) az[j] = (bf16_t)0.f;
  if (g < 2) {
    if (WS) az = ld8((const float*)rbf3 + (size_t)(grow0 + rc) * 16 + (g << 3));
    else    az = ld8((const bf16_t*)rbf3 + (size_t)(grow0 + rc) * 16 + (g << 3));
  }
  f32x4 ag[8];
  zero8(ag);
#pragma unroll
  for (int nt = 0; nt < 8; ++nt) {
    ag[nt] = MFMA(az, *(const bf16x8*)&Wrl[(nt * 64 + lane) << 3], ag[nt]);
    if (WS) ag[nt] = MFMA(az, *(const bf16x8*)&Wrl[4096 + ((nt * 64 + lane) << 3)], ag[nt]);
  }
  f32x4 am[8];
  zero8(am);
  if (WS) issue512(s4, Wm + 16384, tid);
  pass_glob<4, 8>(am, af, Wb, lane);
  if (WS) {
    commit512(s4, Wb + 16384, tid);
    __syncthreads();
    pass_glob<4, 8>(am, af, Wb + 16384, lane);
  }
  bf16_t* op = out + (size_t)(grow0 + g * 4) * 128 + rc;
#pragma unroll
  for (int nt = 0; nt < 8; ++nt)
#pragma unroll
    for (int r = 0; r < 4; ++r)
      op[(size_t)r * 128 + nt * 16] = (bf16_t)(siluf(am[nt][r]) * ag[nt][r]);
}

__global__ __launch_bounds__(512, 2) void k_mkt2(const int* __restrict__ flag,
    const void* __restrict__ mst, const void* __restrict__ rbf3,
    const bf16_t* __restrict__ Wm, const bf16_t* __restrict__ Wr,
    bf16_t* __restrict__ out) {
  __shared__ __align__(16) bf16_t Wb[2 * 16384];
  __shared__ __align__(16) bf16_t Wrl[8192];
  if (*flag) mkt_body<true>(Wb, Wrl, mst, rbf3, Wm, Wr, out, threadIdx.x, blockIdx.x);
  else       mkt_body<false>(Wb, Wrl, mst, rbf3, Wm, Wr, out, threadIdx.x, blockIdx.x);
}

// ---- gemmE body: A(M x 128) @ W(128 x 64), 64 rows/block, 256 thr ----
template <bool AF32, bool WS>
__device__ __forceinline__ void gemmE_body(bf16_t* Wb, const void* A, const bf16_t* W,
                                           bf16_t* out, int tid, int bx) {
  const int lane = tid & 63, wid = tid >> 6;
  const int grow0 = bx * 64 + wid * 16;
  const int rc = lane & 15, g = lane >> 4;
  St4 s4;
  issue256(s4, W, tid);
  commit256(s4, Wb, tid);
  __syncthreads();
  bf16x8 af[4];
  ldAt<AF32>(af, A, (size_t)(grow0 + rc), g);
  f32x4 acc[4];
  zero4(acc);
  if (WS) issue256(s4, W + 8192, tid);
  pass_glob<4, 4>(acc, af, Wb, lane);
  if (WS) {
    commit256(s4, Wb + 8192, tid);
    __syncthreads();
    pass_glob<4, 4>(acc, af, Wb + 8192, lane);
  }
  bf16_t* op = out + (size_t)(grow0 + g * 4) * 64 + rc;
#pragma unroll
  for (int nt = 0; nt < 4; ++nt)
#pragma unroll
    for (int r = 0; r < 4; ++r) op[(size_t)r * 64 + nt * 16] = (bf16_t)siluf(acc[nt][r]);
}

__global__ __launch_bounds__(256, 4) void k_gemmE2(const int* __restrict__ flag, int a_rt,
    const void* __restrict__ A, const bf16_t* __restrict__ W, bf16_t* __restrict__ out) {
  __shared__ __align__(16) bf16_t Wb[2 * 8192];
  if (*flag) {
    if (a_rt) gemmE_body<true, true>(Wb, A, W, out, threadIdx.x, blockIdx.x);
    else      gemmE_body<false, true>(Wb, A, W, out, threadIdx.x, blockIdx.x);
  } else {
    gemmE_body<false, false>(Wb, A, W, out, threadIdx.x, blockIdx.x);
  }
}

// ---- gemmN body: A(N x 128, f32) @ W(128 x 128), 128 rows/block, partial-safe ----
template <bool WS>
__device__ __forceinline__ void gemmN_body(bf16_t* Wb, const float* A, const bf16_t* W,
                                           bf16_t* out, int M, int tid, int bx) {
  const int lane = tid & 63, wid = tid >> 6;
  const int grow0 = bx * 128 + wid * 16;
  const bool act = grow0 < M;
  const int rc = lane & 15, g = lane >> 4;
  Sw4 s4;
  issue512(s4, W, tid);
  commit512(s4, Wb, tid);
  __syncthreads();
  bf16x8 af[4];
  if (act) {
    const float* q = A + (size_t)(grow0 + rc) * 128 + (g << 3);
#pragma unroll
    for (int ks = 0; ks < 4; ++ks) af[ks] = ld8(q + ks * 32);
  } else {
#pragma unroll
    for (int ks = 0; ks < 4; ++ks)
#pragma unroll
      for (int j = 0; j < 8; ++j) af[ks][j] = (bf16_t)0.f;
  }
  f32x4 acc[8];
  zero8(acc);
  if (WS) issue512(s4, W + 16384, tid);
  pass_glob<4, 8>(acc, af, Wb, lane);
  if (WS) {
    commit512(s4, Wb + 16384, tid);
    __syncthreads();
    pass_glob<4, 8>(acc, af, Wb + 16384, lane);
  }
  if (act) {
    bf16_t* op = out + (size_t)(grow0 + g * 4) * 128 + rc;
#pragma unroll
    for (int nt = 0; nt < 8; ++nt)
#pragma unroll
      for (int r = 0; r < 4; ++r) op[(size_t)r * 128 + nt * 16] = (bf16_t)siluf(acc[nt][r]);
  }
}

__global__ __launch_bounds__(512, 2) void k_gemmN2(const int* __restrict__ flag,
    const float* __restrict__ A, const bf16_t* __restrict__ W, bf16_t* __restrict__ out,
    int M) {
  __shared__ __align__(16) bf16_t Wb[2 * 16384];
  if (*flag) gemmN_body<true>(Wb, A, W, out, M, threadIdx.x, blockIdx.x);
  else       gemmN_body<false>(Wb, A, W, out, M, threadIdx.x, blockIdx.x);
}

// ---- combine body: 128 rows/block, 5 logical GEMMs, dbuf weights ----
template <bool WS>
__device__ __forceinline__ void comb_body(bf16_t* Wb,
    const void* mst, const bf16_t* xt, const bf16_t* xq, const int* idx_swap,
    const bf16_t* Wsk, const bf16_t* Wtst, const bf16_t* Wtts,
    const bf16_t* Wqst, const bf16_t* Wqts, bf16_t* X, int tid, int bx) {
  const int lane = tid & 63, wid = tid >> 6;
  const int grow0 = bx * 128 + wid * 16;
  const int rc = lane & 15, g = lane >> 4;
  const int arow = grow0 + rc;
  const int srow = idx_swap[arow];
  const bf16_t* wseq[5] = {Wsk, Wtst, Wtts, Wqst, Wqts};
  const int SZs[5] = {16384, 8192, 8192, 8192, 8192};
  Sw4 s4;
  issue512(s4, wseq[0], tid);
  commit512(s4, Wb, tid);
  __syncthreads();
  int cur = 0;
  constexpr int NP = WS ? 2 : 1;
  f32x4 total[8], acc[8];
  zero8(acc);
  bf16x8 af[4];
#pragma unroll
  for (int l = 0; l < 5; ++l) {
    if (l == 0) {
      ldAt<WS>(af, mst, (size_t)arow, g);
    } else {
      const bf16_t* asrc = (l <= 2) ? xt : xq;
      int r = (l == 1 || l == 3) ? arow : srow;
      af[0] = ld8(asrc + (size_t)r * 64 + (g << 3));
      af[1] = ld8(asrc + (size_t)r * 64 + 32 + (g << 3));
    }
#pragma unroll
    for (int p = 0; p < NP; ++p) {
      const bool last = (l == 4) && (p == NP - 1);
      if (!last) issue512(s4, (WS && p == 0) ? wseq[l] + SZs[l] : wseq[l + 1], tid);
      if (l == 0) pass_glob<4, 8>(acc, af, Wb + cur * 16384, lane);
      else        pass_glob<2, 8>(acc, af, Wb + cur * 16384, lane);
      if (!last) {
        commit512(s4, Wb + (cur ^ 1) * 16384, tid);
        __syncthreads();
        cur ^= 1;
      }
    }
    if (l == 0) {
#pragma unroll
      for (int nt = 0; nt < 8; ++nt) total[nt] = acc[nt] * INV_SQRT_3;
    } else {
#pragma unroll
      for (int nt = 0; nt < 8; ++nt)
#pragma unroll
        for (int r = 0; r < 4; ++r)
          total[nt][r] += siluf(acc[nt][r]) * (INV_SQRT_2 * INV_SQRT_3);
    }
    zero8(acc);
  }
  bf16_t* op = X + (size_t)(grow0 + g * 4) * 128 + rc;
#pragma unroll
  for (int nt = 0; nt < 8; ++nt)
#pragma unroll
    for (int r = 0; r < 4; ++r) op[(size_t)r * 128 + nt * 16] = (bf16_t)total[nt][r];
}

__global__ __launch_bounds__(512, 2) void k_comb2(const int* __restrict__ flag,
    const void* __restrict__ mst, const bf16_t* __restrict__ xt,
    const bf16_t* __restrict__ xq, const int* __restrict__ idx_swap,
    const bf16_t* Wsk, const bf16_t* Wtst, const bf16_t* Wtts,
    const bf16_t* Wqst, const bf16_t* Wqts, bf16_t* __restrict__ X) {
  __shared__ __align__(16) bf16_t Wb[2 * 16384];
  if (*flag) comb_body<true>(Wb, mst, xt, xq, idx_swap, Wsk, Wtst, Wtts, Wqst, Wqts, X,
                             threadIdx.x, blockIdx.x);
  else       comb_body<false>(Wb, mst, xt, xq, idx_swap, Wsk, Wtst, Wtts, Wqst, Wqts, X,
                              threadIdx.x, blockIdx.x);
}

// ---- resE body: res_before + mst-mix + res_after(2 layers); 128 rows, dbuf ----
template <bool WS>
__device__ __forceinline__ void resE_body(bf16_t* Xs, bf16_t* Ys, bf16_t* Wb,
    const bf16_t* Xg, const void* mst,
    const bf16_t* W0, const bf16_t* W1, const bf16_t* W2,
    const bf16_t* W3, const bf16_t* W4, const bf16_t* W5,
    bf16_t* outg, int tid, int bx) {
  const int lane = tid & 63, wid = tid >> 6;
  const int grow0 = bx * 128 + wid * 16;
  const int rc = lane & 15, g = lane >> 4;
  bf16_t* slabX = Xs + wid * (16 * 136);
  bf16_t* slabY = Ys + wid * (16 * 136);
  constexpr int NW = WS ? 12 : 6;
  const bf16_t* seq[NW];
  const bf16_t* Wl[6] = {W0, W1, W2, W3, W4, W5};
  if (WS) {
#pragma unroll
    for (int l = 0; l < 6; ++l) { seq[2 * l] = Wl[l]; seq[2 * l + 1] = Wl[l] + 16384; }
  } else {
#pragma unroll
    for (int l = 0; l < 6; ++l) seq[l] = Wl[l];
  }
  Sw4 s4;
  issue512(s4, seq[0], tid);
#pragma unroll
  for (int i = 0; i < 4; ++i) {
    int o = (i * 64 + lane) * 8, r = o >> 7, c = o & 127;
    *(bf16x8*)&slabX[r * 136 + c] = *(const bf16x8*)&Xg[(size_t)(grow0 + r) * 128 + c];
  }
  commit512(s4, Wb, tid);
  __syncthreads();
  f32x4 acc[8];
  zero8(acc);
  int cur = 0;
#pragma unroll
  for (int s = 0; s < NW; ++s) {
    if (s + 1 < NW) issue512(s4, seq[s + 1], tid);
    const int gg = WS ? (s >> 1) : s;
    const bool fin = WS ? ((s & 1) != 0) : true;
    pass_slab<4>(acc, (gg & 1) ? slabY : slabX, Wb + cur * 16384, lane);
    if (fin) {
      if ((gg & 1) == 0) {
#pragma unroll
        for (int nt = 0; nt < 8; ++nt)
#pragma unroll
          for (int r = 0; r < 4; ++r)
            slabY[(g * 4 + r) * 136 + nt * 16 + rc] = (bf16_t)siluf(acc[nt][r]);
      } else {
#pragma unroll
        for (int nt = 0; nt < 8; ++nt)
#pragma unroll
          for (int r = 0; r < 4; ++r) {
            int ix = (g * 4 + r) * 136 + nt * 16 + rc;
            float v = ((float)slabX[ix] + siluf(acc[nt][r])) * INV_SQRT_2;
            if (gg == 1)
              v = (ldsc(mst, WS, (size_t)(grow0 + g * 4 + r) * 128 + nt * 16 + rc) + v) *
                  INV_SQRT_2;
            slabX[ix] = (bf16_t)v;
          }
      }
      zero8(acc);
    }
    if (s + 1 < NW) {
      commit512(s4, Wb + (cur ^ 1) * 16384, tid);
      __syncthreads();
      cur ^= 1;
    }
  }
#pragma unroll
  for (int i = 0; i < 4; ++i) {
    int o = (i * 64 + lane) * 8, r = o >> 7, c = o & 127;
    *(bf16x8*)&outg[(size_t)(grow0 + r) * 128 + c] = *(const bf16x8*)&slabX[r * 136 + c];
  }
}

__global__ __launch_bounds__(512, 1) void k_resE2(const int* __restrict__ flag,
    const bf16_t* __restrict__ Xg, const void* __restrict__ mst,
    const bf16_t* W0, const bf16_t* W1, const bf16_t* W2,
    const bf16_t* W3, const bf16_t* W4, const bf16_t* W5,
    bf16_t* __restrict__ outg) {
  __shared__ __align__(16) bf16_t Xs[128 * 136];
  __shared__ __align__(16) bf16_t Ys[128 * 136];
  __shared__ __align__(16) bf16_t Wb[2 * 16384];
  if (*flag) resE_body<true>(Xs, Ys, Wb, Xg, mst, W0, W1, W2, W3, W4, W5, outg,
                             threadIdx.x, blockIdx.x);
  else       resE_body<false>(Xs, Ys, Wb, Xg, mst, W0, W1, W2, W3, W4, W5, outg,
                              threadIdx.x, blockIdx.x);
}

// ---- resN body: 2-layer residual stack in place; 128 rows, partial-safe ----
template <bool WS>
__device__ __forceinline__ void resN_body(bf16_t* Xs, bf16_t* Ys, bf16_t* Wb,
    bf16_t* Xg, const bf16_t* W0, const bf16_t* W1, const bf16_t* W2, const bf16_t* W3,
    int M, int tid, int bx) {
  const int lane = tid & 63, wid = tid >> 6;
  const int grow0 = bx * 128 + wid * 16;
  const bool act = grow0 < M;
  const int rc = lane & 15, g = lane >> 4;
  bf16_t* slabX = Xs + wid * (16 * 136);
  bf16_t* slabY = Ys + wid * (16 * 136);
  constexpr int NW = WS ? 8 : 4;
  const bf16_t* seq[NW];
  const bf16_t* Wl[4] = {W0, W1, W2, W3};
  if (WS) {
#pragma unroll
    for (int l = 0; l < 4; ++l) { seq[2 * l] = Wl[l]; seq[2 * l + 1] = Wl[l] + 16384; }
  } else {
#pragma unroll
    for (int l = 0; l < 4; ++l) seq[l] = Wl[l];
  }
  Sw4 s4;
  issue512(s4, seq[0], tid);
  if (act) {
#pragma unroll
    for (int i = 0; i < 4; ++i) {
      int o = (i * 64 + lane) * 8, r = o >> 7, c = o & 127;
      *(bf16x8*)&slabX[r * 136 + c] = *(const bf16x8*)&Xg[(size_t)(grow0 + r) * 128 + c];
    }
  }
  commit512(s4, Wb, tid);
  __syncthreads();
  f32x4 acc[8];
  zero8(acc);
  int cur = 0;
#pragma unroll
  for (int s = 0; s < NW; ++s) {
    if (s + 1 < NW) issue512(s4, seq[s + 1], tid);
    const int gg = WS ? (s >> 1) : s;
    const bool fin = WS ? ((s & 1) != 0) : true;
    pass_slab<4>(acc, (gg & 1) ? slabY : slabX, Wb + cur * 16384, lane);
    if (fin) {
      if ((gg & 1) == 0) {
#pragma unroll
        for (int nt = 0; nt < 8; ++nt)
#pragma unroll
          for (int r = 0; r < 4; ++r)
            slabY[(g * 4 + r) * 136 + nt * 16 + rc] = (bf16_t)siluf(acc[nt][r]);
      } else {
#pragma unroll
        for (int nt = 0; nt < 8; ++nt)
#pragma unroll
          for (int r = 0; r < 4; ++r) {
            int ix = (g * 4 + r) * 136 + nt * 16 + rc;
            slabX[ix] = (bf16_t)(((float)slabX[ix] + siluf(acc[nt][r])) * INV_SQRT_2);
          }
      }
      zero8(acc);
    }
    if (s + 1 < NW) {
      commit512(s4, Wb + (cur ^ 1) * 16384, tid);
      __syncthreads();
      cur ^= 1;
    }
  }
  if (act) {
#pragma unroll
    for (int i = 0; i < 4; ++i) {
      int o = (i * 64 + lane) * 8, r = o >> 7, c = o & 127;
      *(bf16x8*)&Xg[(size_t)(grow0 + r) * 128 + c] = *(const bf16x8*)&slabX[r * 136 + c];
    }
  }
}

__global__ __launch_bounds__(512, 1) void k_resN2(const int* __restrict__ flag,
    bf16_t* __restrict__ Xg, const bf16_t* W0, const bf16_t* W1,
    const bf16_t* W2, const bf16_t* W3, int M) {
  __shared__ __align__(16) bf16_t Xs[128 * 136];
  __shared__ __align__(16) bf16_t Ys[128 * 136];
  __shared__ __align__(16) bf16_t Wb[2 * 16384];
  if (*flag) resN_body<true>(Xs, Ys, Wb, Xg, W0, W1, W2, W3, M, threadIdx.x, blockIdx.x);
  else       resN_body<false>(Xs, Ys, Wb, Xg, W0, W1, W2, W3, M, threadIdx.x, blockIdx.x);
}

// ---- ASI body: K=384 gathered + res_m + final combine; 128 rows, dbuf ----
// outm is indexed in OUTPUT ELEMENTS at offset eoff (= N*128): dtype-agnostic.
template <bool WS>
__device__ __forceinline__ void asi_body(bf16_t* Xs, bf16_t* Ys, bf16_t* Wb,
    const bf16_t* hnew, const bf16_t* m, const int* idx_s, const int* idx_t,
    const bf16_t* Wasi, const bf16_t* Wm0, const bf16_t* Wm1,
    void* outm, int eoff, int tid, int bx) {
  const int lane = tid & 63, wid = tid >> 6;
  const int grow0 = bx * 128 + wid * 16;
  const int rc = lane & 15, g = lane >> 4;
  bf16_t* slabX = Xs + wid * (16 * 136);
  bf16_t* slabY = Ys + wid * (16 * 136);
  const int e = grow0 + rc;
  const int rs = idx_s[e], rt = idx_t[e];
  constexpr int NW = WS ? 10 : 5;
  const bf16_t* seq[NW];
  if (WS) {
    seq[0] = Wasi;         seq[1] = Wasi + 49152;
    seq[2] = Wasi + 16384; seq[3] = Wasi + 65536;
    seq[4] = Wasi + 32768; seq[5] = Wasi + 81920;
    seq[6] = Wm0;          seq[7] = Wm0 + 16384;
    seq[8] = Wm1;          seq[9] = Wm1 + 16384;
  } else {
    seq[0] = Wasi; seq[1] = Wasi + 16384; seq[2] = Wasi + 32768;
    seq[3] = Wm0;  seq[4] = Wm1;
  }
  Sw4 s4;
  issue512(s4, seq[0], tid);
  commit512(s4, Wb, tid);
  __syncthreads();
  f32x4 acc[8];
  zero8(acc);
  bf16x8 af[4];
  int cur = 0;
#pragma unroll
  for (int s = 0; s < NW; ++s) {
    if (s + 1 < NW) issue512(s4, seq[s + 1], tid);
    const int lg = WS ? (s >> 1) : s;
    const bool first = WS ? ((s & 1) == 0) : true;
    const bool fin = WS ? ((s & 1) != 0) : true;
    if (lg <= 2) {
      if (first) {
        const bf16_t* asrc = (lg == 0) ? hnew + (size_t)rs * 128
                           : (lg == 1) ? hnew + (size_t)rt * 128
                                       : m + (size_t)e * 128;
#pragma unroll
        for (int ks = 0; ks < 4; ++ks) af[ks] = ld8(asrc + ks * 32 + (g << 3));
      }
      pass_glob<4, 8>(acc, af, Wb + cur * 16384, lane);
    } else if (lg == 3) {
      pass_slab<4>(acc, slabX, Wb + cur * 16384, lane);
    } else {
      pass_slab<4>(acc, slabY, Wb + cur * 16384, lane);
    }
    if (fin) {
      if (lg == 2) {
#pragma unroll
        for (int nt = 0; nt < 8; ++nt)
#pragma unroll
          for (int r = 0; r < 4; ++r)
            slabX[(g * 4 + r) * 136 + nt * 16 + rc] = (bf16_t)siluf(acc[nt][r]);
        zero8(acc);
      } else if (lg == 3) {
#pragma unroll
        for (int nt = 0; nt < 8; ++nt)
#pragma unroll
          for (int r = 0; r < 4; ++r)
            slabY[(g * 4 + r) * 136 + nt * 16 + rc] = (bf16_t)siluf(acc[nt][r]);
        zero8(acc);
      } else if (lg == 4) {
#pragma unroll
        for (int nt = 0; nt < 8; ++nt)
#pragma unroll
          for (int r = 0; r < 4; ++r) {
            int row = grow0 + g * 4 + r, col = nt * 16 + rc;
            float x = (float)slabX[(g * 4 + r) * 136 + col];
            float v = (x + siluf(acc[nt][r])) * INV_SQRT_2;
            float res = (toF(m[(size_t)row * 128 + col]) + v) * INV_SQRT_2;
            size_t oi = (size_t)eoff + (size_t)row * 128 + col;
            if (WS) ((float*)outm)[oi] = res;
            else    ((bf16_t*)outm)[oi] = (bf16_t)res;
          }
      }
    }
    if (s + 1 < NW) {
      commit512(s4, Wb + (cur ^ 1) * 16384, tid);
      __syncthreads();
      cur ^= 1;
    }
  }
}

__global__ __launch_bounds__(512, 1) void k_asi2(const int* __restrict__ flag,
    const bf16_t* __restrict__ hnew, const bf16_t* __restrict__ m,
    const int* __restrict__ idx_s, const int* __restrict__ idx_t,
    const bf16_t* Wasi, const bf16_t* Wm0, const bf16_t* Wm1,
    void* __restrict__ outm, int eoff) {
  __shared__ __align__(16) bf16_t Xs[128 * 136];
  __shared__ __align__(16) bf16_t Ys[128 * 136];
  __shared__ __align__(16) bf16_t Wb[2 * 16384];
  if (*flag) asi_body<true>(Xs, Ys, Wb, hnew, m, idx_s, idx_t, Wasi, Wm0, Wm1, outm, eoff,
                            threadIdx.x, blockIdx.x);
  else       asi_body<false>(Xs, Ys, Wb, hnew, m, idx_s, idx_t, Wasi, Wm0, Wm1, outm, eoff,
                             threadIdx.x, blockIdx.x);
}

// ---- atom embedding scatter ----
__global__ void k_scatter(const int* __restrict__ flag, const bf16_t* __restrict__ m,
                          const void* __restrict__ rbf_h, const void* __restrict__ Wrbf,
                          const int* __restrict__ idx_t, float* __restrict__ h2) {
  const int ws = *flag;
  int e = blockIdx.x;
  int c = threadIdx.x;
  float gt = 0.f;
  if (ws) {
    const float* rh = (const float*)rbf_h + (size_t)e * 16;
    const float* w = (const float*)Wrbf;
#pragma unroll
    for (int k = 0; k < 16; ++k) gt += rh[k] * w[k * 128 + c];
  } else {
    const bf16_t* rh = (const bf16_t*)rbf_h + (size_t)e * 16;
    const bf16_t* w = (const bf16_t*)Wrbf;
#pragma unroll
    for (int k = 0; k < 16; ++k) gt += toF(rh[k]) * toF(w[k * 128 + c]);
  }
  atomicAdd(&h2[(size_t)idx_t[e] * 128 + c], toF(m[(size_t)e * 128 + c]) * gt);
}

// ---- h_new = (h + X)*r2 -> out and X (bf16, for ASI) ----
__global__ void k_hnew(const int* __restrict__ flag, const void* __restrict__ h,
                       bf16_t* __restrict__ X, void* __restrict__ out, int n) {
  const int ws = *flag;
  int i = blockIdx.x * blockDim.x + threadIdx.x;
  if (i >= n) return;
  float v = (ldsc(h, ws, i) + toF(X[i])) * INV_SQRT_2;
  X[i] = (bf16_t)v;
  if (ws) ((float*)out)[i] = v;
  else    ((bf16_t*)out)[i] = (bf16_t)v;
}

// ================================================================================
extern "C" void kernel_launch(void* const* d_in, const int* in_sizes, int n_in,
                              void* d_out, int out_size, void* d_ws, size_t ws_size,
                              hipStream_t stream) {
  const int D = 128;
  const int N = in_sizes[0] / D;   // 8000
  const int E = in_sizes[1] / D;   // 80000

  char* base = (char*)d_ws;
  bf16_t* Wpack = (bf16_t*)base;
  int* flag = (int*)(base + 1916928 + 32768);
  char* dyn = base + 1916928 + 32768 + 256;
  size_t U = (size_t)E * 64 * sizeof(bf16_t);
  bf16_t* s0 = (bf16_t*)dyn;
  bf16_t* s1 = (bf16_t*)(dyn + U);
  bf16_t* s2 = (bf16_t*)(dyn + 2 * U);
  bf16_t* s3 = (bf16_t*)(dyn + 3 * U);
  float* h2 = (float*)(dyn + 2 * U);   // reuses X region (dead by then)
  bf16_t* Rn2 = (bf16_t*)((char*)h2 + (size_t)N * 128 * sizeof(float));

  k_detect<<<1, 64, 0, stream>>>((const unsigned short*)d_in[2], flag);

  struct Def { int idx; int Krows; int K, Np, Kpad, bilin; };
  const Def defs[25] = {
      {23, 0, 128, 64, 128, 0},    // 0  Qd
      {17, 0, 128, 128, 128, 0},   // 1  Mkt
      {18, 0, 16, 128, 32, 0},     // 2  Rbf
      {19, 0, 128, 64, 128, 0},    // 3  Td
      {21, 0, 64, 128, 64, 0},     // 4  Tst
      {22, 0, 64, 128, 64, 0},     // 5  Tts
      {25, 0, 64, 128, 64, 0},     // 6  Qst
      {26, 0, 64, 128, 64, 0},     // 7  Qts
      {16, 0, 128, 128, 128, 0},   // 8  Sk
      {27, 0, 128, 128, 128, 0},   // 9  B0
      {27, 128, 128, 128, 128, 0}, // 10 B1
      {28, 0, 128, 128, 128, 0},   // 11 A0
      {28, 128, 128, 128, 128, 0}, // 12 A1
      {28, 256, 128, 128, 128, 0}, // 13 A2
      {28, 384, 128, 128, 128, 0}, // 14 A3
      {29, 0, 128, 128, 128, 0},   // 15 M0
      {29, 128, 128, 128, 128, 0}, // 16 M1
      {31, 0, 128, 128, 128, 0},   // 17 Aed
      {32, 0, 128, 128, 128, 0},   // 18 Ae0
      {32, 128, 128, 128, 128, 0}, // 19 Ae1
      {32, 256, 128, 128, 128, 0}, // 20 Ae2
      {32, 384, 128, 128, 128, 0}, // 21 Ae3
      {33, 0, 384, 128, 384, 0},   // 22 Asi
      {20, 0, 1024, 64, 1024, 1},  // 23 Tc (bilinear)
      {24, 0, 1024, 64, 1024, 1},  // 24 Qc (bilinear)
  };
  RTable tab;
  int off[25];
  int cur = 0;
  for (int i = 0; i < 25; ++i) {
    off[i] = cur;
    tab.d[i].src = d_in[defs[i].idx];
    tab.d[i].K = defs[i].K;
    tab.d[i].N = defs[i].Np;
    tab.d[i].Kpad = defs[i].Kpad;
    tab.d[i].dstoff = cur;
    tab.d[i].mode = (defs[i].Krows << 1) | defs[i].bilin;
    cur += 2 * defs[i].Kpad * defs[i].Np;
  }

  k_repack<<<dim3(256, 25), 256, 0, stream>>>(flag, tab, Wpack);

  bf16_t* mkt_tmp = s0;  // spans s0+s1 (E x 128)
  bf16_t* m_kt = s2;
  bf16_t* m_d  = s3;
  bf16_t* xt = s0;
  bf16_t* xq = s1;
  bf16_t* X  = s2;       // spans s2+s3 (E x 128)
  bf16_t* R2 = s0;       // spans s0+s1 (E x 128)

  const int gE128 = E / 128;            // 625
  const int gE64  = E / 64;             // 1250
  const int gN128 = (N + 127) / 128;    // 63 (partial last block)

  k_mkt2<<<gE128, 512, 0, stream>>>(flag, d_in[1], d_in[3], Wpack + off[1], Wpack + off[2],
                                    mkt_tmp);
  k_gemmE2<<<gE64, 256, 0, stream>>>(flag, 0, mkt_tmp, Wpack + off[3], m_kt);
  k_gemmE2<<<gE64, 256, 0, stream>>>(flag, 1, d_in[1], Wpack + off[0], m_d);
  k_bil<<<E / 16, 256, 0, stream>>>(flag, d_in[4], m_kt, (const int*)d_in[9], Wpack + off[23],
                                    xt);
  k_bil<<<E / 16, 256, 0, stream>>>(flag, d_in[5], m_d, (const int*)d_in[12], Wpack + off[24],
                                    xq);
  k_comb2<<<gE128, 512, 0, stream>>>(flag, d_in[1], xt, xq, (const int*)d_in[8],
      Wpack + off[8], Wpack + off[4], Wpack + off[5], Wpack + off[6], Wpack + off[7], X);
  k_resE2<<<gE128, 512, 0, stream>>>(flag, X, d_in[1], Wpack + off[9], Wpack + off[10],
      Wpack + off[11], Wpack + off[12], Wpack + off[13], Wpack + off[14], R2);
  k_zero<<<(N * 128 + 255) / 256, 256, 0, stream>>>(h2, N * 128);
  k_scatter<<<E, 128, 0, stream>>>(flag, R2, d_in[2], d_in[30], (const int*)d_in[7], h2);
  k_gemmN2<<<gN128, 512, 0, stream>>>(flag, h2, Wpack + off[17], Rn2, N);
  k_resN2<<<gN128, 512, 0, stream>>>(flag, Rn2, Wpack + off[18], Wpack + off[19],
                                     Wpack + off[20], Wpack + off[21], N);
  k_hnew<<<(N * 128 + 255) / 256, 256, 0, stream>>>(flag, d_in[0], Rn2, d_out, N * 128);
  k_asi2<<<gE128, 512, 0, stream>>>(flag, Rn2, R2, (const int*)d_in[6], (const int*)d_in[7],
      Wpack + off[22], Wpack + off[15], Wpack + off[16], d_out, N * 128);
}

// Round 10
// 616.549 us; speedup vs baseline: 1.2026x; 1.0788x over previous
//
#include <hip/hip_runtime.h>

#define INV_SQRT_2 0.70710678118654752440f
#define INV_SQRT_3 0.57735026918962576451f

typedef __bf16 bf16_t;
typedef __bf16 bf16x8 __attribute__((ext_vector_type(8)));
typedef __bf16 bf16x4 __attribute__((ext_vector_type(4)));
typedef float f32x4 __attribute__((ext_vector_type(4)));

__device__ __forceinline__ float toF(float x) { return x; }
__device__ __forceinline__ float toF(bf16_t x) { return (float)x; }
// silu via v_rcp_f32 (1-ulp approx; bf16 output rounding absorbs it)
__device__ __forceinline__ float siluf(float x) {
  return x * __builtin_amdgcn_rcpf(1.f + __expf(-x));
}

__device__ __forceinline__ bf16x8 ld8(const bf16_t* p) { return *(const bf16x8*)p; }
__device__ __forceinline__ bf16x8 ld8(const float* p) {
  bf16x8 r;
#pragma unroll
  for (int j = 0; j < 8; ++j) r[j] = (bf16_t)p[j];
  return r;
}

__device__ __forceinline__ float ldsc(const void* p, int f32, size_t i) {
  return f32 ? ((const float*)p)[i] : toF(((const bf16_t*)p)[i]);
}

__device__ __forceinline__ f32x4 MFMA(bf16x8 a, bf16x8 b, f32x4 c) {
  return __builtin_amdgcn_mfma_f32_16x16x32_bf16(a, b, c, 0, 0, 0);
}

__device__ __forceinline__ void zero8(f32x4 (&a)[8]) {
#pragma unroll
  for (int i = 0; i < 8; ++i)
#pragma unroll
    for (int q = 0; q < 4; ++q) a[i][q] = 0.f;
}
__device__ __forceinline__ void zero4(f32x4 (&a)[4]) {
#pragma unroll
  for (int i = 0; i < 4; ++i)
#pragma unroll
    for (int q = 0; q < 4; ++q) a[i][q] = 0.f;
}

// Packed-B fragment: element j of lane l = B[ks*32 + (l>>4)*8 + j][nt*16 + (l&15)]
__device__ __forceinline__ bf16x8 ldB(const bf16_t* Bp, int ks, int nt, int NT, int lane) {
  return *(const bf16x8*)(Bp + ((((size_t)ks * NT + nt) * 64 + lane) << 3));
}

// A-fragment loader, compile-time dtype
template <bool F32>
__device__ __forceinline__ void ldAt(bf16x8 (&af)[4], const void* p, size_t row, int g) {
  if (F32) {
    const float* q = (const float*)p + row * 128 + (g << 3);
#pragma unroll
    for (int ks = 0; ks < 4; ++ks) af[ks] = ld8(q + ks * 32);
  } else {
    const bf16_t* q = (const bf16_t*)p + row * 128 + (g << 3);
#pragma unroll
    for (int ks = 0; ks < 4; ++ks) af[ks] = ld8(q + ks * 32);
  }
}

// ---- weight staging, 512-thread blocks: 32 KB via 4 chunks ----
struct Sw4 { bf16x8 v[4]; };
__device__ __forceinline__ void issue512(Sw4& r, const bf16_t* src, int tid) {
#pragma unroll
  for (int i = 0; i < 4; ++i) r.v[i] = *(const bf16x8*)(src + ((i * 512 + tid) << 3));
}
__device__ __forceinline__ void commit512(const Sw4& r, bf16_t* dst, int tid) {
#pragma unroll
  for (int i = 0; i < 4; ++i) *(bf16x8*)&dst[(i * 512 + tid) << 3] = r.v[i];
}
// ---- weight staging, 512-thread blocks: 16 KB half via 2 chunks ----
struct Sh2 { bf16x8 v[2]; };
__device__ __forceinline__ void issueH(Sh2& r, const bf16_t* src, int tid) {
#pragma unroll
  for (int i = 0; i < 2; ++i) r.v[i] = *(const bf16x8*)(src + ((i * 512 + tid) << 3));
}
__device__ __forceinline__ void commitH(const Sh2& r, bf16_t* dst, int tid) {
#pragma unroll
  for (int i = 0; i < 2; ++i) *(bf16x8*)&dst[(i * 512 + tid) << 3] = r.v[i];
}
// ---- weight staging, 256-thread blocks: 16 KB ----
struct St4 { bf16x8 v[4]; };
__device__ __forceinline__ void issue256(St4& r, const bf16_t* src, int tid) {
#pragma unroll
  for (int i = 0; i < 4; ++i) r.v[i] = *(const bf16x8*)(src + ((i * 256 + tid) << 3));
}
__device__ __forceinline__ void commit256(const St4& r, bf16_t* dst, int tid) {
#pragma unroll
  for (int i = 0; i < 4; ++i) *(bf16x8*)&dst[(i * 256 + tid) << 3] = r.v[i];
}

// ---- MFMA pass over 16 rows from A-frag regs; B from LDS ----
template <int KS, int NT>
__device__ __forceinline__ void pass_glob(f32x4 (&acc)[NT], const bf16x8* af,
                                          const bf16_t* Wbuf, int lane) {
#pragma unroll
  for (int ks = 0; ks < KS; ++ks)
#pragma unroll
    for (int nt = 0; nt < NT; ++nt)
      acc[nt] = MFMA(af[ks], *(const bf16x8*)&Wbuf[((ks * NT + nt) * 64 + lane) << 3], acc[nt]);
}
// ---- half MFMA pass: 2 ks x 8 nt; A fragments as args, B from 16 KB LDS half ----
__device__ __forceinline__ void pass_halfW(f32x4 (&acc)[8], bf16x8 a0, bf16x8 a1,
                                           const bf16_t* Wh, int lane) {
#pragma unroll
  for (int nt = 0; nt < 8; ++nt)
    acc[nt] = MFMA(a0, *(const bf16x8*)&Wh[(nt * 64 + lane) << 3], acc[nt]);
#pragma unroll
  for (int nt = 0; nt < 8; ++nt)
    acc[nt] = MFMA(a1, *(const bf16x8*)&Wh[((8 + nt) * 64 + lane) << 3], acc[nt]);
}

// ---- dtype detector ----
__global__ void k_detect(const unsigned short* __restrict__ probe, int* __restrict__ flag) {
  __shared__ int cnt;
  if (threadIdx.x == 0) cnt = 0;
  __syncthreads();
  int bad = 0;
  for (int i = threadIdx.x; i < 256; i += 64) {
    unsigned int u = (unsigned int)probe[i] << 16;
    float v = __uint_as_float(u);
    if (!(v == v) || fabsf(v) > 4.f || v < -0.25f) bad++;
  }
  atomicAdd(&cnt, bad);
  __syncthreads();
  if (threadIdx.x == 0) *flag = (cnt > 16) ? 1 : 0;
}

__global__ void k_zero(float* __restrict__ p, int n) {
  int i = blockIdx.x * blockDim.x + threadIdx.x;
  if (i < n) p[i] = 0.f;
}

// ---------------- weight repack: W(KxN) -> fragment-linear [hi|lo] ----------------
struct RDesc { const void* src; int K, N, Kpad, dstoff, mode; };
struct RTable { RDesc d[25]; };

__global__ void k_repack(const int* __restrict__ flag, RTable tab, bf16_t* __restrict__ out) {
  const int ws = *flag;
  RDesc d = tab.d[blockIdx.y];
  int p = blockIdx.x * 256 + threadIdx.x;
  int sz = d.Kpad * d.N;
  if (p >= sz) return;
  const int bilin = d.mode & 1;
  const int Koff = d.mode >> 1;
  int NT = d.N >> 4;
  int j = p & 7;
  int lane = (p >> 3) & 63;
  int q = p >> 9;
  int nt = q % NT, ks = q / NT;
  int k = ks * 32 + ((lane >> 4) << 3) + j;
  int col = nt * 16 + (lane & 15);
  size_t si = bilin ? ((size_t)(k & 63) * 16 + (k >> 6)) * 64 + col
                    : (size_t)(k + Koff) * d.N + col;
  float v = (k < d.K) ? ldsc(d.src, ws, si) : 0.f;
  bf16_t hi = (bf16_t)v;
  out[d.dstoff + p] = hi;
  out[d.dstoff + sz + p] = (bf16_t)(v - (float)hi);
}

// ---- MFMA bilinear: 16 edges/block, 256 threads ----
__global__ __launch_bounds__(256) void k_bil(const int* __restrict__ flag,
    const void* __restrict__ basis, const bf16_t* __restrict__ msrc,
    const int* __restrict__ gidx, const bf16_t* __restrict__ Wc,
    bf16_t* __restrict__ out) {
  const int ws = *flag;
  __shared__ __align__(16) bf16_t Ms[96 * 72];
  __shared__ __align__(16) float Bas[16 * 100];
  __shared__ __align__(16) bf16_t P[16384];
  const int tid = threadIdx.x;
  const int e0 = blockIdx.x * 16;
#pragma unroll
  for (int it = 0; it < 3; ++it) {
    int c = tid + it * 256;
    int j = c >> 3, part = c & 7;
    int row = gidx[e0 * 6 + j];
    *(bf16x8*)&Ms[j * 72 + part * 8] = ld8(msrc + (size_t)row * 64 + part * 8);
  }
#pragma unroll
  for (int it = 0; it < 6; ++it) {
    int c = tid + it * 256;
    Bas[(c / 96) * 100 + (c % 96)] = ldsc(basis, ws, (size_t)e0 * 96 + c);
  }
  __syncthreads();
  {
    const int e = tid >> 4, sub = tid & 15, i0 = sub * 4;
    float acc[16][4];
#pragma unroll
    for (int b = 0; b < 16; ++b)
#pragma unroll
      for (int j = 0; j < 4; ++j) acc[b][j] = 0.f;
#pragma unroll
    for (int k = 0; k < 6; ++k) {
      bf16x4 mv = *(const bf16x4*)&Ms[(e * 6 + k) * 72 + i0];
      float mf[4];
#pragma unroll
      for (int j = 0; j < 4; ++j) mf[j] = (float)mv[j];
      const float* bp = &Bas[e * 100 + k * 16];
#pragma unroll
      for (int b4 = 0; b4 < 4; ++b4) {
        f32x4 bv = *(const f32x4*)&bp[b4 * 4];
#pragma unroll
        for (int bb = 0; bb < 4; ++bb)
#pragma unroll
          for (int j = 0; j < 4; ++j) acc[b4 * 4 + bb][j] += bv[bb] * mf[j];
      }
    }
#pragma unroll
    for (int b = 0; b < 16; ++b) {
      int kk = b * 64 + i0;
      int ks = kk >> 5, r5 = kk & 31;
      int lane_hi = r5 >> 3, jj = r5 & 7;
      bf16x4 w;
#pragma unroll
      for (int j = 0; j < 4; ++j) w[j] = (bf16_t)acc[b][j];
      *(bf16x4*)&P[ks * 512 + lane_hi * 128 + e * 8 + jj] = w;
    }
  }
  __syncthreads();
  const int lane = tid & 63, wid = tid >> 6;
  const int rc = lane & 15, g = lane >> 4;
  f32x4 oa[4];
  zero4(oa);
  if (ws) {
#pragma unroll
    for (int k4 = 0; k4 < 8; ++k4)
#pragma unroll
      for (int j = 0; j < 4; ++j) {
        int ks = k4 * 4 + j;
        bf16x8 a = *(const bf16x8*)&P[ks * 512 + lane * 8];
        oa[j] = MFMA(a, ldB(Wc, ks, wid, 4, lane), oa[j]);
        oa[j] = MFMA(a, ldB(Wc + 65536, ks, wid, 4, lane), oa[j]);
      }
  } else {
#pragma unroll
    for (int k4 = 0; k4 < 8; ++k4)
#pragma unroll
      for (int j = 0; j < 4; ++j) {
        int ks = k4 * 4 + j;
        bf16x8 a = *(const bf16x8*)&P[ks * 512 + lane * 8];
        oa[j] = MFMA(a, ldB(Wc, ks, wid, 4, lane), oa[j]);
      }
  }
  f32x4 oacc = (oa[0] + oa[1]) + (oa[2] + oa[3]);
  bf16_t* op = out + ((size_t)e0 + g * 4) * 64 + wid * 16 + rc;
#pragma unroll
  for (int r = 0; r < 4; ++r) op[(size_t)r * 64] = (bf16_t)oacc[r];
}

// ================= templated bodies (compile-time WS) =================

// ---- m_kt body ----
template <bool WS>
__device__ __forceinline__ void mkt_body(bf16_t* Wb, bf16_t* Wrl,
    const void* mst, const void* rbf3, const bf16_t* Wm, const bf16_t* Wr,
    bf16_t* out, int tid, int bx) {
  const int lane = tid & 63, wid = tid >> 6;
  const int grow0 = bx * 128 + wid * 16;
  const int rc = lane & 15, g = lane >> 4;
  Sw4 s4;
  issue512(s4, Wm, tid);
  bf16x8 wr0 = *(const bf16x8*)(Wr + (tid << 3));
  bf16x8 wr1 = *(const bf16x8*)(Wr + 4096 + (tid << 3));
  commit512(s4, Wb, tid);
  *(bf16x8*)&Wrl[tid << 3] = wr0;
  *(bf16x8*)&Wrl[4096 + (tid << 3)] = wr1;
  __syncthreads();
  bf16x8 af[4];
  ldAt<WS>(af, mst, (size_t)(grow0 + rc), g);
  bf16x8 az;
#pragma unroll
  for (int j = 0; j < 8; ++j) az[j] = (bf16_t)0.f;
  if (g < 2) {
    if (WS) az = ld8((const float*)rbf3 + (size_t)(grow0 + rc) * 16 + (g << 3));
    else    az = ld8((const bf16_t*)rbf3 + (size_t)(grow0 + rc) * 16 + (g << 3));
  }
  f32x4 ag[8];
  zero8(ag);
#pragma unroll
  for (int nt = 0; nt < 8; ++nt) {
    ag[nt] = MFMA(az, *(const bf16x8*)&Wrl[(nt * 64 + lane) << 3], ag[nt]);
    if (WS) ag[nt] = MFMA(az, *(const bf16x8*)&Wrl[4096 + ((nt * 64 + lane) << 3)], ag[nt]);
  }
  f32x4 am[8];
  zero8(am);
  if (WS) issue512(s4, Wm + 16384, tid);
  pass_glob<4, 8>(am, af, Wb, lane);
  if (WS) {
    commit512(s4, Wb + 16384, tid);
    __syncthreads();
    pass_glob<4, 8>(am, af, Wb + 16384, lane);
  }
  bf16_t* op = out + (size_t)(grow0 + g * 4) * 128 + rc;
#pragma unroll
  for (int nt = 0; nt < 8; ++nt)
#pragma unroll
    for (int r = 0; r < 4; ++r)
      op[(size_t)r * 128 + nt * 16] = (bf16_t)(siluf(am[nt][r]) * ag[nt][r]);
}

__global__ __launch_bounds__(512, 2) void k_mkt2(const int* __restrict__ flag,
    const void* __restrict__ mst, const void* __restrict__ rbf3,
    const bf16_t* __restrict__ Wm, const bf16_t* __restrict__ Wr,
    bf16_t* __restrict__ out) {
  __shared__ __align__(16) bf16_t Wb[2 * 16384];
  __shared__ __align__(16) bf16_t Wrl[8192];
  if (*flag) mkt_body<true>(Wb, Wrl, mst, rbf3, Wm, Wr, out, threadIdx.x, blockIdx.x);
  else       mkt_body<false>(Wb, Wrl, mst, rbf3, Wm, Wr, out, threadIdx.x, blockIdx.x);
}

// ---- gemmE body: A(M x 128) @ W(128 x 64), 64 rows/block, 256 thr ----
template <bool AF32, bool WS>
__device__ __forceinline__ void gemmE_body(bf16_t* Wb, const void* A, const bf16_t* W,
                                           bf16_t* out, int tid, int bx) {
  const int lane = tid & 63, wid = tid >> 6;
  const int grow0 = bx * 64 + wid * 16;
  const int rc = lane & 15, g = lane >> 4;
  St4 s4;
  issue256(s4, W, tid);
  commit256(s4, Wb, tid);
  __syncthreads();
  bf16x8 af[4];
  ldAt<AF32>(af, A, (size_t)(grow0 + rc), g);
  f32x4 acc[4];
  zero4(acc);
  if (WS) issue256(s4, W + 8192, tid);
  pass_glob<4, 4>(acc, af, Wb, lane);
  if (WS) {
    commit256(s4, Wb + 8192, tid);
    __syncthreads();
    pass_glob<4, 4>(acc, af, Wb + 8192, lane);
  }
  bf16_t* op = out + (size_t)(grow0 + g * 4) * 64 + rc;
#pragma unroll
  for (int nt = 0; nt < 4; ++nt)
#pragma unroll
    for (int r = 0; r < 4; ++r) op[(size_t)r * 64 + nt * 16] = (bf16_t)siluf(acc[nt][r]);
}

__global__ __launch_bounds__(256, 4) void k_gemmE2(const int* __restrict__ flag, int a_rt,
    const void* __restrict__ A, const bf16_t* __restrict__ W, bf16_t* __restrict__ out) {
  __shared__ __align__(16) bf16_t Wb[2 * 8192];
  if (*flag) {
    if (a_rt) gemmE_body<true, true>(Wb, A, W, out, threadIdx.x, blockIdx.x);
    else      gemmE_body<false, true>(Wb, A, W, out, threadIdx.x, blockIdx.x);
  } else {
    gemmE_body<false, false>(Wb, A, W, out, threadIdx.x, blockIdx.x);
  }
}

// ---- gemmN body: A(N x 128, f32) @ W(128 x 128), 128 rows/block, partial-safe ----
template <bool WS>
__device__ __forceinline__ void gemmN_body(bf16_t* Wb, const float* A, const bf16_t* W,
                                           bf16_t* out, int M, int tid, int bx) {
  const int lane = tid & 63, wid = tid >> 6;
  const int grow0 = bx * 128 + wid * 16;
  const bool act = grow0 < M;
  const int rc = lane & 15, g = lane >> 4;
  Sw4 s4;
  issue512(s4, W, tid);
  commit512(s4, Wb, tid);
  __syncthreads();
  bf16x8 af[4];
  if (act) {
    const float* q = A + (size_t)(grow0 + rc) * 128 + (g << 3);
#pragma unroll
    for (int ks = 0; ks < 4; ++ks) af[ks] = ld8(q + ks * 32);
  } else {
#pragma unroll
    for (int ks = 0; ks < 4; ++ks)
#pragma unroll
      for (int j = 0; j < 8; ++j) af[ks][j] = (bf16_t)0.f;
  }
  f32x4 acc[8];
  zero8(acc);
  if (WS) issue512(s4, W + 16384, tid);
  pass_glob<4, 8>(acc, af, Wb, lane);
  if (WS) {
    commit512(s4, Wb + 16384, tid);
    __syncthreads();
    pass_glob<4, 8>(acc, af, Wb + 16384, lane);
  }
  if (act) {
    bf16_t* op = out + (size_t)(grow0 + g * 4) * 128 + rc;
#pragma unroll
    for (int nt = 0; nt < 8; ++nt)
#pragma unroll
      for (int r = 0; r < 4; ++r) op[(size_t)r * 128 + nt * 16] = (bf16_t)siluf(acc[nt][r]);
  }
}

__global__ __launch_bounds__(512, 2) void k_gemmN2(const int* __restrict__ flag,
    const float* __restrict__ A, const bf16_t* __restrict__ W, bf16_t* __restrict__ out,
    int M) {
  __shared__ __align__(16) bf16_t Wb[2 * 16384];
  if (*flag) gemmN_body<true>(Wb, A, W, out, M, threadIdx.x, blockIdx.x);
  else       gemmN_body<false>(Wb, A, W, out, M, threadIdx.x, blockIdx.x);
}

// ---- combine body: 128 rows/block, 5 logical GEMMs, dbuf weights ----
template <bool WS>
__device__ __forceinline__ void comb_body(bf16_t* Wb,
    const void* mst, const bf16_t* xt, const bf16_t* xq, const int* idx_swap,
    const bf16_t* Wsk, const bf16_t* Wtst, const bf16_t* Wtts,
    const bf16_t* Wqst, const bf16_t* Wqts, bf16_t* X, int tid, int bx) {
  const int lane = tid & 63, wid = tid >> 6;
  const int grow0 = bx * 128 + wid * 16;
  const int rc = lane & 15, g = lane >> 4;
  const int arow = grow0 + rc;
  const int srow = idx_swap[arow];
  const bf16_t* wseq[5] = {Wsk, Wtst, Wtts, Wqst, Wqts};
  const int SZs[5] = {16384, 8192, 8192, 8192, 8192};
  Sw4 s4;
  issue512(s4, wseq[0], tid);
  commit512(s4, Wb, tid);
  __syncthreads();
  int cur = 0;
  constexpr int NP = WS ? 2 : 1;
  f32x4 total[8], acc[8];
  zero8(acc);
  bf16x8 af[4];
#pragma unroll
  for (int l = 0; l < 5; ++l) {
    if (l == 0) {
      ldAt<WS>(af, mst, (size_t)arow, g);
    } else {
      const bf16_t* asrc = (l <= 2) ? xt : xq;
      int r = (l == 1 || l == 3) ? arow : srow;
      af[0] = ld8(asrc + (size_t)r * 64 + (g << 3));
      af[1] = ld8(asrc + (size_t)r * 64 + 32 + (g << 3));
    }
#pragma unroll
    for (int p = 0; p < NP; ++p) {
      const bool last = (l == 4) && (p == NP - 1);
      if (!last) issue512(s4, (WS && p == 0) ? wseq[l] + SZs[l] : wseq[l + 1], tid);
      if (l == 0) pass_glob<4, 8>(acc, af, Wb + cur * 16384, lane);
      else        pass_glob<2, 8>(acc, af, Wb + cur * 16384, lane);
      if (!last) {
        commit512(s4, Wb + (cur ^ 1) * 16384, tid);
        __syncthreads();
        cur ^= 1;
      }
    }
    if (l == 0) {
#pragma unroll
      for (int nt = 0; nt < 8; ++nt) total[nt] = acc[nt] * INV_SQRT_3;
    } else {
#pragma unroll
      for (int nt = 0; nt < 8; ++nt)
#pragma unroll
        for (int r = 0; r < 4; ++r)
          total[nt][r] += siluf(acc[nt][r]) * (INV_SQRT_2 * INV_SQRT_3);
    }
    zero8(acc);
  }
  bf16_t* op = X + (size_t)(grow0 + g * 4) * 128 + rc;
#pragma unroll
  for (int nt = 0; nt < 8; ++nt)
#pragma unroll
    for (int r = 0; r < 4; ++r) op[(size_t)r * 128 + nt * 16] = (bf16_t)total[nt][r];
}

__global__ __launch_bounds__(512, 2) void k_comb2(const int* __restrict__ flag,
    const void* __restrict__ mst, const bf16_t* __restrict__ xt,
    const bf16_t* __restrict__ xq, const int* __restrict__ idx_swap,
    const bf16_t* Wsk, const bf16_t* Wtst, const bf16_t* Wtts,
    const bf16_t* Wqst, const bf16_t* Wqts, bf16_t* __restrict__ X) {
  __shared__ __align__(16) bf16_t Wb[2 * 16384];
  if (*flag) comb_body<true>(Wb, mst, xt, xq, idx_swap, Wsk, Wtst, Wtts, Wqst, Wqts, X,
                             threadIdx.x, blockIdx.x);
  else       comb_body<false>(Wb, mst, xt, xq, idx_swap, Wsk, Wtst, Wtts, Wqst, Wqts, X,
                              threadIdx.x, blockIdx.x);
}

// ---- resE body v2: wave-private single slab + xa-in-regs + 16KB-half dbuf ----
// LDS: Sl 34816 B + Wb 32768 B = 67584 B -> 2 blocks/CU (16 waves).
template <bool WS>
__device__ __forceinline__ void resE_body(bf16_t* Sl, bf16_t* Wb,
    const bf16_t* Xg, const void* mst,
    const bf16_t* W0, const bf16_t* W1, const bf16_t* W2,
    const bf16_t* W3, const bf16_t* W4, const bf16_t* W5,
    bf16_t* outg, int tid, int bx) {
  const int lane = tid & 63, wid = tid >> 6;
  const int grow0 = bx * 128 + wid * 16;
  const int rc = lane & 15, g = lane >> 4;
  bf16_t* sl = Sl + wid * 2176;
  constexpr int NW = WS ? 12 : 6;
  const bf16_t* seq[NW];
  const bf16_t* Wl[6] = {W0, W1, W2, W3, W4, W5};
  if (WS) {
#pragma unroll
    for (int l = 0; l < 6; ++l) { seq[2 * l] = Wl[l]; seq[2 * l + 1] = Wl[l] + 16384; }
  } else {
#pragma unroll
    for (int l = 0; l < 6; ++l) seq[l] = Wl[l];
  }
  Sh2 sh;
  issueH(sh, seq[0], tid);
#pragma unroll
  for (int i = 0; i < 4; ++i) {
    int o = (i * 64 + lane) * 8, r = o >> 7, c = o & 127;
    *(bf16x8*)&sl[r * 136 + c] = *(const bf16x8*)&Xg[(size_t)(grow0 + r) * 128 + c];
  }
  commitH(sh, Wb, tid);
  __syncthreads();
  f32x4 xa[8];
#pragma unroll
  for (int nt = 0; nt < 8; ++nt)
#pragma unroll
    for (int r = 0; r < 4; ++r)
      xa[nt][r] = (float)sl[(g * 4 + r) * 136 + nt * 16 + rc];
  f32x4 acc[8];
  zero8(acc);
  int cur = 0;
  constexpr int CNT = 2 * NW;
#pragma unroll
  for (int i = 0; i < CNT; ++i) {
    const int s = i >> 1, h = i & 1;
    if (i + 1 < CNT) issueH(sh, seq[(i + 1) >> 1] + ((i + 1) & 1) * 8192, tid);
    bf16x8 a0 = *(const bf16x8*)&sl[rc * 136 + (h * 2) * 32 + (g << 3)];
    bf16x8 a1 = *(const bf16x8*)&sl[rc * 136 + (h * 2 + 1) * 32 + (g << 3)];
    pass_halfW(acc, a0, a1, Wb + cur * 8192, lane);
    if (h == 1) {
      const bool fin = WS ? ((s & 1) != 0) : true;
      const int gg = WS ? (s >> 1) : s;
      if (fin) {
        if ((gg & 1) == 0) {
#pragma unroll
          for (int nt = 0; nt < 8; ++nt)
#pragma unroll
            for (int r = 0; r < 4; ++r)
              sl[(g * 4 + r) * 136 + nt * 16 + rc] = (bf16_t)siluf(acc[nt][r]);
        } else {
#pragma unroll
          for (int nt = 0; nt < 8; ++nt)
#pragma unroll
            for (int r = 0; r < 4; ++r) {
              float v = (xa[nt][r] + siluf(acc[nt][r])) * INV_SQRT_2;
              if (gg == 1)
                v = (ldsc(mst, WS, (size_t)(grow0 + g * 4 + r) * 128 + nt * 16 + rc) + v) *
                    INV_SQRT_2;
              bf16_t vb = (bf16_t)v;
              xa[nt][r] = (float)vb;
              sl[(g * 4 + r) * 136 + nt * 16 + rc] = vb;
            }
        }
        zero8(acc);
      }
    }
    if (i + 1 < CNT) {
      commitH(sh, Wb + (cur ^ 1) * 8192, tid);
      __syncthreads();
      cur ^= 1;
    }
  }
#pragma unroll
  for (int i = 0; i < 4; ++i) {
    int o = (i * 64 + lane) * 8, r = o >> 7, c = o & 127;
    *(bf16x8*)&outg[(size_t)(grow0 + r) * 128 + c] = *(const bf16x8*)&sl[r * 136 + c];
  }
}

__global__ __launch_bounds__(512, 4) void k_resE2(const int* __restrict__ flag,
    const bf16_t* __restrict__ Xg, const void* __restrict__ mst,
    const bf16_t* W0, const bf16_t* W1, const bf16_t* W2,
    const bf16_t* W3, const bf16_t* W4, const bf16_t* W5,
    bf16_t* __restrict__ outg) {
  __shared__ __align__(16) bf16_t Sl[17408];
  __shared__ __align__(16) bf16_t Wb[16384];
  if (*flag) resE_body<true>(Sl, Wb, Xg, mst, W0, W1, W2, W3, W4, W5, outg,
                             threadIdx.x, blockIdx.x);
  else       resE_body<false>(Sl, Wb, Xg, mst, W0, W1, W2, W3, W4, W5, outg,
                              threadIdx.x, blockIdx.x);
}

// ---- resN body v2: same engine, in place, partial-safe ----
template <bool WS>
__device__ __forceinline__ void resN_body(bf16_t* Sl, bf16_t* Wb,
    bf16_t* Xg, const bf16_t* W0, const bf16_t* W1, const bf16_t* W2, const bf16_t* W3,
    int M, int tid, int bx) {
  const int lane = tid & 63, wid = tid >> 6;
  const int grow0 = bx * 128 + wid * 16;
  const bool act = grow0 < M;
  const int rc = lane & 15, g = lane >> 4;
  bf16_t* sl = Sl + wid * 2176;
  constexpr int NW = WS ? 8 : 4;
  const bf16_t* seq[NW];
  const bf16_t* Wl[4] = {W0, W1, W2, W3};
  if (WS) {
#pragma unroll
    for (int l = 0; l < 4; ++l) { seq[2 * l] = Wl[l]; seq[2 * l + 1] = Wl[l] + 16384; }
  } else {
#pragma unroll
    for (int l = 0; l < 4; ++l) seq[l] = Wl[l];
  }
  Sh2 sh;
  issueH(sh, seq[0], tid);
  if (act) {
#pragma unroll
    for (int i = 0; i < 4; ++i) {
      int o = (i * 64 + lane) * 8, r = o >> 7, c = o & 127;
      *(bf16x8*)&sl[r * 136 + c] = *(const bf16x8*)&Xg[(size_t)(grow0 + r) * 128 + c];
    }
  }
  commitH(sh, Wb, tid);
  __syncthreads();
  f32x4 xa[8];
#pragma unroll
  for (int nt = 0; nt < 8; ++nt)
#pragma unroll
    for (int r = 0; r < 4; ++r)
      xa[nt][r] = (float)sl[(g * 4 + r) * 136 + nt * 16 + rc];
  f32x4 acc[8];
  zero8(acc);
  int cur = 0;
  constexpr int CNT = 2 * NW;
#pragma unroll
  for (int i = 0; i < CNT; ++i) {
    const int s = i >> 1, h = i & 1;
    if (i + 1 < CNT) issueH(sh, seq[(i + 1) >> 1] + ((i + 1) & 1) * 8192, tid);
    bf16x8 a0 = *(const bf16x8*)&sl[rc * 136 + (h * 2) * 32 + (g << 3)];
    bf16x8 a1 = *(const bf16x8*)&sl[rc * 136 + (h * 2 + 1) * 32 + (g << 3)];
    pass_halfW(acc, a0, a1, Wb + cur * 8192, lane);
    if (h == 1) {
      const bool fin = WS ? ((s & 1) != 0) : true;
      const int gg = WS ? (s >> 1) : s;
      if (fin) {
        if ((gg & 1) == 0) {
#pragma unroll
          for (int nt = 0; nt < 8; ++nt)
#pragma unroll
            for (int r = 0; r < 4; ++r)
              sl[(g * 4 + r) * 136 + nt * 16 + rc] = (bf16_t)siluf(acc[nt][r]);
        } else {
#pragma unroll
          for (int nt = 0; nt < 8; ++nt)
#pragma unroll
            for (int r = 0; r < 4; ++r) {
              float v = (xa[nt][r] + siluf(acc[nt][r])) * INV_SQRT_2;
              bf16_t vb = (bf16_t)v;
              xa[nt][r] = (float)vb;
              sl[(g * 4 + r) * 136 + nt * 16 + rc] = vb;
            }
        }
        zero8(acc);
      }
    }
    if (i + 1 < CNT) {
      commitH(sh, Wb + (cur ^ 1) * 8192, tid);
      __syncthreads();
      cur ^= 1;
    }
  }
  if (act) {
#pragma unroll
    for (int i = 0; i < 4; ++i) {
      int o = (i * 64 + lane) * 8, r = o >> 7, c = o & 127;
      *(bf16x8*)&Xg[(size_t)(grow0 + r) * 128 + c] = *(const bf16x8*)&sl[r * 136 + c];
    }
  }
}

__global__ __launch_bounds__(512, 4) void k_resN2(const int* __restrict__ flag,
    bf16_t* __restrict__ Xg, const bf16_t* W0, const bf16_t* W1,
    const bf16_t* W2, const bf16_t* W3, int M) {
  __shared__ __align__(16) bf16_t Sl[17408];
  __shared__ __align__(16) bf16_t Wb[16384];
  if (*flag) resN_body<true>(Sl, Wb, Xg, W0, W1, W2, W3, M, threadIdx.x, blockIdx.x);
  else       resN_body<false>(Sl, Wb, Xg, W0, W1, W2, W3, M, threadIdx.x, blockIdx.x);
}

// ---- ASI body v2: gathered K=384 + res_m + final combine; same engine ----
template <bool WS>
__device__ __forceinline__ void asi_body(bf16_t* Sl, bf16_t* Wb,
    const bf16_t* hnew, const bf16_t* m, const int* idx_s, const int* idx_t,
    const bf16_t* Wasi, const bf16_t* Wm0, const bf16_t* Wm1,
    void* outm, int eoff, int tid, int bx) {
  const int lane = tid & 63, wid = tid >> 6;
  const int grow0 = bx * 128 + wid * 16;
  const int rc = lane & 15, g = lane >> 4;
  bf16_t* sl = Sl + wid * 2176;
  const int e = grow0 + rc;
  const int rs = idx_s[e], rt = idx_t[e];
  constexpr int NW = WS ? 10 : 5;
  const bf16_t* seq[NW];
  if (WS) {
    seq[0] = Wasi;         seq[1] = Wasi + 49152;
    seq[2] = Wasi + 16384; seq[3] = Wasi + 65536;
    seq[4] = Wasi + 32768; seq[5] = Wasi + 81920;
    seq[6] = Wm0;          seq[7] = Wm0 + 16384;
    seq[8] = Wm1;          seq[9] = Wm1 + 16384;
  } else {
    seq[0] = Wasi; seq[1] = Wasi + 16384; seq[2] = Wasi + 32768;
    seq[3] = Wm0;  seq[4] = Wm1;
  }
  Sh2 sh;
  issueH(sh, seq[0], tid);
  commitH(sh, Wb, tid);
  __syncthreads();
  f32x4 acc[8];
  zero8(acc);
  f32x4 xa[8];
  bf16x8 af[4];
  int cur = 0;
  constexpr int CNT = 2 * NW;
#pragma unroll
  for (int i = 0; i < CNT; ++i) {
    const int s = i >> 1, h = i & 1;
    const int lg = WS ? (s >> 1) : s;
    const bool firstm = WS ? ((s & 1) == 0) : true;
    if (i + 1 < CNT) issueH(sh, seq[(i + 1) >> 1] + ((i + 1) & 1) * 8192, tid);
    bf16x8 a0, a1;
    if (lg <= 2) {
      if (h == 0 && firstm) {
        const bf16_t* asrc = (lg == 0) ? hnew + (size_t)rs * 128
                           : (lg == 1) ? hnew + (size_t)rt * 128
                                       : m + (size_t)e * 128;
#pragma unroll
        for (int ks = 0; ks < 4; ++ks) af[ks] = ld8(asrc + ks * 32 + (g << 3));
      }
      a0 = af[h * 2];
      a1 = af[h * 2 + 1];
    } else {
      a0 = *(const bf16x8*)&sl[rc * 136 + (h * 2) * 32 + (g << 3)];
      a1 = *(const bf16x8*)&sl[rc * 136 + (h * 2 + 1) * 32 + (g << 3)];
    }
    pass_halfW(acc, a0, a1, Wb + cur * 8192, lane);
    if (h == 1) {
      const bool fin = WS ? ((s & 1) != 0) : true;
      if (fin) {
        if (lg == 2) {
#pragma unroll
          for (int nt = 0; nt < 8; ++nt)
#pragma unroll
            for (int r = 0; r < 4; ++r) {
              bf16_t vb = (bf16_t)siluf(acc[nt][r]);
              sl[(g * 4 + r) * 136 + nt * 16 + rc] = vb;
              xa[nt][r] = (float)vb;
            }
          zero8(acc);
        } else if (lg == 3) {
#pragma unroll
          for (int nt = 0; nt < 8; ++nt)
#pragma unroll
            for (int r = 0; r < 4; ++r)
              sl[(g * 4 + r) * 136 + nt * 16 + rc] = (bf16_t)siluf(acc[nt][r]);
          zero8(acc);
        } else if (lg == 4) {
#pragma unroll
          for (int nt = 0; nt < 8; ++nt)
#pragma unroll
            for (int r = 0; r < 4; ++r) {
              int row = grow0 + g * 4 + r, col = nt * 16 + rc;
              float v = (xa[nt][r] + siluf(acc[nt][r])) * INV_SQRT_2;
              float res = (toF(m[(size_t)row * 128 + col]) + v) * INV_SQRT_2;
              size_t oi = (size_t)eoff + (size_t)row * 128 + col;
              if (WS) ((float*)outm)[oi] = res;
              else    ((bf16_t*)outm)[oi] = (bf16_t)res;
            }
        }
      }
    }
    if (i + 1 < CNT) {
      commitH(sh, Wb + (cur ^ 1) * 8192, tid);
      __syncthreads();
      cur ^= 1;
    }
  }
}

__global__ __launch_bounds__(512, 4) void k_asi2(const int* __restrict__ flag,
    const bf16_t* __restrict__ hnew, const bf16_t* __restrict__ m,
    const int* __restrict__ idx_s, const int* __restrict__ idx_t,
    const bf16_t* Wasi, const bf16_t* Wm0, const bf16_t* Wm1,
    void* __restrict__ outm, int eoff) {
  __shared__ __align__(16) bf16_t Sl[17408];
  __shared__ __align__(16) bf16_t Wb[16384];
  if (*flag) asi_body<true>(Sl, Wb, hnew, m, idx_s, idx_t, Wasi, Wm0, Wm1, outm, eoff,
                            threadIdx.x, blockIdx.x);
  else       asi_body<false>(Sl, Wb, hnew, m, idx_s, idx_t, Wasi, Wm0, Wm1, outm, eoff,
                             threadIdx.x, blockIdx.x);
}

// ---- atom embedding scatter ----
__global__ void k_scatter(const int* __restrict__ flag, const bf16_t* __restrict__ m,
                          const void* __restrict__ rbf_h, const void* __restrict__ Wrbf,
                          const int* __restrict__ idx_t, float* __restrict__ h2) {
  const int ws = *flag;
  int e = blockIdx.x;
  int c = threadIdx.x;
  float gt = 0.f;
  if (ws) {
    const float* rh = (const float*)rbf_h + (size_t)e * 16;
    const float* w = (const float*)Wrbf;
#pragma unroll
    for (int k = 0; k < 16; ++k) gt += rh[k] * w[k * 128 + c];
  } else {
    const bf16_t* rh = (const bf16_t*)rbf_h + (size_t)e * 16;
    const bf16_t* w = (const bf16_t*)Wrbf;
#pragma unroll
    for (int k = 0; k < 16; ++k) gt += toF(rh[k]) * toF(w[k * 128 + c]);
  }
  atomicAdd(&h2[(size_t)idx_t[e] * 128 + c], toF(m[(size_t)e * 128 + c]) * gt);
}

// ---- h_new = (h + X)*r2 -> out and X (bf16, for ASI) ----
__global__ void k_hnew(const int* __restrict__ flag, const void* __restrict__ h,
                       bf16_t* __restrict__ X, void* __restrict__ out, int n) {
  const int ws = *flag;
  int i = blockIdx.x * blockDim.x + threadIdx.x;
  if (i >= n) return;
  float v = (ldsc(h, ws, i) + toF(X[i])) * INV_SQRT_2;
  X[i] = (bf16_t)v;
  if (ws) ((float*)out)[i] = v;
  else    ((bf16_t*)out)[i] = (bf16_t)v;
}

// ================================================================================
extern "C" void kernel_launch(void* const* d_in, const int* in_sizes, int n_in,
                              void* d_out, int out_size, void* d_ws, size_t ws_size,
                              hipStream_t stream) {
  const int D = 128;
  const int N = in_sizes[0] / D;   // 8000
  const int E = in_sizes[1] / D;   // 80000

  char* base = (char*)d_ws;
  bf16_t* Wpack = (bf16_t*)base;
  int* flag = (int*)(base + 1916928 + 32768);
  char* dyn = base + 1916928 + 32768 + 256;
  size_t U = (size_t)E * 64 * sizeof(bf16_t);
  bf16_t* s0 = (bf16_t*)dyn;
  bf16_t* s1 = (bf16_t*)(dyn + U);
  bf16_t* s2 = (bf16_t*)(dyn + 2 * U);
  bf16_t* s3 = (bf16_t*)(dyn + 3 * U);
  float* h2 = (float*)(dyn + 2 * U);   // reuses X region (dead by then)
  bf16_t* Rn2 = (bf16_t*)((char*)h2 + (size_t)N * 128 * sizeof(float));

  k_detect<<<1, 64, 0, stream>>>((const unsigned short*)d_in[2], flag);

  struct Def { int idx; int Krows; int K, Np, Kpad, bilin; };
  const Def defs[25] = {
      {23, 0, 128, 64, 128, 0},    // 0  Qd
      {17, 0, 128, 128, 128, 0},   // 1  Mkt
      {18, 0, 16, 128, 32, 0},     // 2  Rbf
      {19, 0, 128, 64, 128, 0},    // 3  Td
      {21, 0, 64, 128, 64, 0},     // 4  Tst
      {22, 0, 64, 128, 64, 0},     // 5  Tts
      {25, 0, 64, 128, 64, 0},     // 6  Qst
      {26, 0, 64, 128, 64, 0},     // 7  Qts
      {16, 0, 128, 128, 128, 0},   // 8  Sk
      {27, 0, 128, 128, 128, 0},   // 9  B0
      {27, 128, 128, 128, 128, 0}, // 10 B1
      {28, 0, 128, 128, 128, 0},   // 11 A0
      {28, 128, 128, 128, 128, 0}, // 12 A1
      {28, 256, 128, 128, 128, 0}, // 13 A2
      {28, 384, 128, 128, 128, 0}, // 14 A3
      {29, 0, 128, 128, 128, 0},   // 15 M0
      {29, 128, 128, 128, 128, 0}, // 16 M1
      {31, 0, 128, 128, 128, 0},   // 17 Aed
      {32, 0, 128, 128, 128, 0},   // 18 Ae0
      {32, 128, 128, 128, 128, 0}, // 19 Ae1
      {32, 256, 128, 128, 128, 0}, // 20 Ae2
      {32, 384, 128, 128, 128, 0}, // 21 Ae3
      {33, 0, 384, 128, 384, 0},   // 22 Asi
      {20, 0, 1024, 64, 1024, 1},  // 23 Tc (bilinear)
      {24, 0, 1024, 64, 1024, 1},  // 24 Qc (bilinear)
  };
  RTable tab;
  int off[25];
  int cur = 0;
  for (int i = 0; i < 25; ++i) {
    off[i] = cur;
    tab.d[i].src = d_in[defs[i].idx];
    tab.d[i].K = defs[i].K;
    tab.d[i].N = defs[i].Np;
    tab.d[i].Kpad = defs[i].Kpad;
    tab.d[i].dstoff = cur;
    tab.d[i].mode = (defs[i].Krows << 1) | defs[i].bilin;
    cur += 2 * defs[i].Kpad * defs[i].Np;
  }

  k_repack<<<dim3(256, 25), 256, 0, stream>>>(flag, tab, Wpack);

  bf16_t* mkt_tmp = s0;  // spans s0+s1 (E x 128)
  bf16_t* m_kt = s2;
  bf16_t* m_d  = s3;
  bf16_t* xt = s0;
  bf16_t* xq = s1;
  bf16_t* X  = s2;       // spans s2+s3 (E x 128)
  bf16_t* R2 = s0;       // spans s0+s1 (E x 128)

  const int gE128 = E / 128;            // 625
  const int gE64  = E / 64;             // 1250
  const int gN128 = (N + 127) / 128;    // 63 (partial last block)

  k_mkt2<<<gE128, 512, 0, stream>>>(flag, d_in[1], d_in[3], Wpack + off[1], Wpack + off[2],
                                    mkt_tmp);
  k_gemmE2<<<gE64, 256, 0, stream>>>(flag, 0, mkt_tmp, Wpack + off[3], m_kt);
  k_gemmE2<<<gE64, 256, 0, stream>>>(flag, 1, d_in[1], Wpack + off[0], m_d);
  k_bil<<<E / 16, 256, 0, stream>>>(flag, d_in[4], m_kt, (const int*)d_in[9], Wpack + off[23],
                                    xt);
  k_bil<<<E / 16, 256, 0, stream>>>(flag, d_in[5], m_d, (const int*)d_in[12], Wpack + off[24],
                                    xq);
  k_comb2<<<gE128, 512, 0, stream>>>(flag, d_in[1], xt, xq, (const int*)d_in[8],
      Wpack + off[8], Wpack + off[4], Wpack + off[5], Wpack + off[6], Wpack + off[7], X);
  k_resE2<<<gE128, 512, 0, stream>>>(flag, X, d_in[1], Wpack + off[9], Wpack + off[10],
      Wpack + off[11], Wpack + off[12], Wpack + off[13], Wpack + off[14], R2);
  k_zero<<<(N * 128 + 255) / 256, 256, 0, stream>>>(h2, N * 128);
  k_scatter<<<E, 128, 0, stream>>>(flag, R2, d_in[2], d_in[30], (const int*)d_in[7], h2);
  k_gemmN2<<<gN128, 512, 0, stream>>>(flag, h2, Wpack + off[17], Rn2, N);
  k_resN2<<<gN128, 512, 0, stream>>>(flag, Rn2, Wpack + off[18], Wpack + off[19],
                                     Wpack + off[20], Wpack + off[21], N);
  k_hnew<<<(N * 128 + 255) / 256, 256, 0, stream>>>(flag, d_in[0], Rn2, d_out, N * 128);
  k_asi2<<<gE128, 512, 0, stream>>>(flag, Rn2, R2, (const int*)d_in[6], (const int*)d_in[7],
      Wpack + off[22], Wpack + off[15], Wpack + off[16], d_out, N * 128);
}